// Round 16
// baseline (377.094 us; speedup 1.0000x reference)
//
#include <hip/hip_runtime.h>
#include <hip/hip_bf16.h>

#define N_USERS   50000
#define N_ITEMS   50000
#define N_ENT     100000
#define NE        2000000
#define NNI       1000000
#define DD        64

#define PART_E    12500    // entity rows per XCD partition
#define PART_I    6250     // item/user rows per XCD partition
#define GROUP     125      // rows per sort group
#define NG_E      100      // groups per entity partition
#define NG_M      50       // groups per item/user partition

#define ECAP_E    262144   // per-XCD-bucket capacity, edges (mean 250000)
#define ECAP_M    131072   // per-XCD-bucket capacity, mat   (mean 125000)
#define ST2CAP    2880     // per-group capacity (mean 2500)
#define CHUNK     4096
#define CAPB      640      // L1 LDS per-bucket staging
#define GCAP      96       // L2 LDS per-group staging

// ---------------------------------------------------------------------------
// L1 bucket: edges -> 8 XCD-partition buckets (proven r12).
// val = tail | etype<<17.
// ---------------------------------------------------------------------------
__global__ __launch_bounds__(256) void bucket_edge_L1(
        const int* __restrict__ head, const int* __restrict__ tail,
        const int* __restrict__ etype,
        int* __restrict__ stK, int* __restrict__ stV, int* __restrict__ cur) {
    __shared__ int bufK[8][CAPB];
    __shared__ int bufV[8][CAPB];
    __shared__ int lcnt[8];
    __shared__ int gbase[8];
    const int tid = threadIdx.x;
    const int lane = tid & 63;
    for (int cs = blockIdx.x * CHUNK; cs < NE; cs += gridDim.x * CHUNK) {
        if (tid < 8) lcnt[tid] = 0;
        __syncthreads();
        const int ce = min(cs + CHUNK, NE);
        for (int i0 = cs; i0 < ce; i0 += 256) {
            const int i = i0 + tid;
            const bool valid = i < ce;
            int h = 0, v = 0, b = 8;
            if (valid) {
                h = __builtin_nontemporal_load(head + i);
                v = __builtin_nontemporal_load(tail + i) |
                    (__builtin_nontemporal_load(etype + i) << 17);
                b = h / PART_E;
            }
            unsigned long long m[8];
            #pragma unroll
            for (int k = 0; k < 8; ++k) m[k] = __ballot(b == k);
            int base8 = 0;
            if (lane < 8) base8 = atomicAdd(&lcnt[lane], (int)__popcll(m[lane]));
            if (valid) {
                const int mybase = __shfl(base8, b);
                const int pos = mybase + (int)__popcll(m[b] & ((1ull << lane) - 1ull));
                if (pos < CAPB) { bufK[b][pos] = h; bufV[b][pos] = v; }
                else {
                    const int gp = atomicAdd(&cur[b], 1);
                    stK[(size_t)b * ECAP_E + gp] = h;
                    stV[(size_t)b * ECAP_E + gp] = v;
                }
            }
        }
        __syncthreads();
        if (tid < 8) gbase[tid] = atomicAdd(&cur[tid], min(lcnt[tid], CAPB));
        __syncthreads();
        for (int b = 0; b < 8; ++b) {
            const int nf = min(lcnt[b], CAPB);
            int* dK = stK + (size_t)b * ECAP_E + gbase[b];
            int* dV = stV + (size_t)b * ECAP_E + gbase[b];
            for (int j = tid; j < nf; j += 256) { dK[j] = bufK[b][j]; dV[j] = bufV[b][j]; }
        }
        __syncthreads();
    }
}

// ---------------------------------------------------------------------------
// L1 bucket: mat entries both directions, packed (key<<16)|other. (proven r12)
// ---------------------------------------------------------------------------
__global__ __launch_bounds__(256) void bucket_mat_L1(
        const int* __restrict__ mrow, const int* __restrict__ mcol,
        int* __restrict__ stC, int* __restrict__ curC,
        int* __restrict__ stR, int* __restrict__ curR) {
    __shared__ int bufc[8][CAPB];
    __shared__ int bufr[8][CAPB];
    __shared__ int lc[8], lr[8], gc[8], gr[8];
    const int tid = threadIdx.x;
    const int lane = tid & 63;
    for (int cs = blockIdx.x * CHUNK; cs < NNI; cs += gridDim.x * CHUNK) {
        if (tid < 8) { lc[tid] = 0; lr[tid] = 0; }
        __syncthreads();
        const int ce = min(cs + CHUNK, NNI);
        for (int i0 = cs; i0 < ce; i0 += 256) {
            const int i = i0 + tid;
            const bool valid = i < ce;
            int r = 0, c = 0, bc = 8, br = 8;
            if (valid) {
                r = __builtin_nontemporal_load(mrow + i);
                c = __builtin_nontemporal_load(mcol + i);
                bc = c / PART_I;
                br = r / PART_I;
            }
            unsigned long long mc[8], mrr[8];
            #pragma unroll
            for (int k = 0; k < 8; ++k) { mc[k] = __ballot(bc == k); mrr[k] = __ballot(br == k); }
            int bc8 = 0, br8 = 0;
            if (lane < 8) {
                bc8 = atomicAdd(&lc[lane], (int)__popcll(mc[lane]));
                br8 = atomicAdd(&lr[lane], (int)__popcll(mrr[lane]));
            }
            if (valid) {
                const unsigned long long lt = (1ull << lane) - 1ull;
                int pos = __shfl(bc8, bc) + (int)__popcll(mc[bc] & lt);
                const int vc = (int)(((unsigned)c << 16) | (unsigned)r);
                if (pos < CAPB) bufc[bc][pos] = vc;
                else stC[(size_t)bc * ECAP_M + atomicAdd(&curC[bc], 1)] = vc;
                pos = __shfl(br8, br) + (int)__popcll(mrr[br] & lt);
                const int vr = (int)(((unsigned)r << 16) | (unsigned)c);
                if (pos < CAPB) bufr[br][pos] = vr;
                else stR[(size_t)br * ECAP_M + atomicAdd(&curR[br], 1)] = vr;
            }
        }
        __syncthreads();
        if (tid < 8)       gc[tid]     = atomicAdd(&curC[tid],     min(lc[tid],     CAPB));
        else if (tid < 16) gr[tid - 8] = atomicAdd(&curR[tid - 8], min(lr[tid - 8], CAPB));
        __syncthreads();
        for (int b = 0; b < 8; ++b) {
            int nf = min(lc[b], CAPB);
            int* d = stC + (size_t)b * ECAP_M + gc[b];
            for (int j = tid; j < nf; j += 256) d[j] = bufc[b][j];
            nf = min(lr[b], CAPB);
            d = stR + (size_t)b * ECAP_M + gr[b];
            for (int j = tid; j < nf; j += 256) d[j] = bufr[b][j];
        }
        __syncthreads();
    }
}

// ---------------------------------------------------------------------------
// L2 bucket edges: partition -> 125-row groups. entry: val | rig<<22.
// 1024 threads (proven r12).
// ---------------------------------------------------------------------------
__global__ __launch_bounds__(1024) void bucket_edge_L2(
        const int* __restrict__ stK, const int* __restrict__ stV,
        const int* __restrict__ cur, int* __restrict__ st2,
        int* __restrict__ cur2) {
    __shared__ int buf[NG_E][GCAP];
    __shared__ int lcnt[NG_E];
    const int p = blockIdx.x & 7;
    const int nb = gridDim.x >> 3;
    const int bi = blockIdx.x >> 3;
    const int n = cur[p];
    const int tid = threadIdx.x, w = tid >> 6, lane = tid & 63;
    const int* sK = stK + (size_t)p * ECAP_E;
    const int* sV = stV + (size_t)p * ECAP_E;
    const int pbase = p * PART_E;
    int* cur2p = cur2 + p * NG_E;
    for (int cs = bi * CHUNK; cs < n; cs += nb * CHUNK) {
        for (int t = tid; t < NG_E; t += 1024) lcnt[t] = 0;
        __syncthreads();
        const int ce = min(cs + CHUNK, n);
        for (int i = cs + tid; i < ce; i += 1024) {
            const int local = __builtin_nontemporal_load(sK + i) - pbase;
            const int g = local / GROUP;
            const int rig = local - g * GROUP;
            const int entry = __builtin_nontemporal_load(sV + i) | (rig << 22);
            const int pos = atomicAdd(&lcnt[g], 1);
            if (pos < GCAP) buf[g][pos] = entry;
            else st2[(size_t)(p * NG_E + g) * ST2CAP + atomicAdd(&cur2p[g], 1)] = entry;
        }
        __syncthreads();
        for (int gi = w; gi < NG_E; gi += 16) {
            const int nf = min(lcnt[gi], GCAP);
            int base = 0;
            if (lane == 0 && nf > 0) base = atomicAdd(&cur2p[gi], nf);
            base = __shfl(base, 0);
            int* d = st2 + (size_t)(p * NG_E + gi) * ST2CAP + base;
            for (int j = lane; j < nf; j += 64) d[j] = buf[gi][j];
        }
        __syncthreads();
    }
}

// mat entry: other | rig<<16.  (proven r12, 1024 threads, separate launches)
__global__ __launch_bounds__(1024) void bucket_mat_L2(
        const int* __restrict__ st, const int* __restrict__ cur8,
        int* __restrict__ st2, int* __restrict__ cur2) {
    __shared__ int buf[NG_M][GCAP];
    __shared__ int lcnt[NG_M];
    const int p = blockIdx.x & 7;
    const int nb = gridDim.x >> 3;
    const int bi = blockIdx.x >> 3;
    const int n = cur8[p];
    const int tid = threadIdx.x, w = tid >> 6, lane = tid & 63;
    const int* s = st + (size_t)p * ECAP_M;
    const int pbase = p * PART_I;
    int* cur2p = cur2 + p * NG_M;
    for (int cs = bi * CHUNK; cs < n; cs += nb * CHUNK) {
        for (int t = tid; t < NG_M; t += 1024) lcnt[t] = 0;
        __syncthreads();
        const int ce = min(cs + CHUNK, n);
        for (int i = cs + tid; i < ce; i += 1024) {
            const unsigned u = (unsigned)__builtin_nontemporal_load(s + i);
            const int local = (int)(u >> 16) - pbase;
            const int g = local / GROUP;
            const int rig = local - g * GROUP;
            const int entry = (int)(u & 0xFFFFu) | (rig << 16);
            const int pos = atomicAdd(&lcnt[g], 1);
            if (pos < GCAP) buf[g][pos] = entry;
            else st2[(size_t)(p * NG_M + g) * ST2CAP + atomicAdd(&cur2p[g], 1)] = entry;
        }
        __syncthreads();
        for (int gi = w; gi < NG_M; gi += 16) {
            const int nf = min(lcnt[gi], GCAP);
            int base = 0;
            if (lane == 0 && nf > 0) base = atomicAdd(&cur2p[gi], nf);
            base = __shfl(base, 0);
            int* d = st2 + (size_t)(p * NG_M + gi) * ST2CAP + base;
            for (int j = lane; j < nf; j += 64) d[j] = buf[gi][j];
        }
        __syncthreads();
    }
}

// ---------------------------------------------------------------------------
// Group-local LDS counting sort (proven). Entries retain rig bits.
// ---------------------------------------------------------------------------
template <int SHIFT>
__device__ __forceinline__ void group_sort_body(
        int* __restrict__ st2, const int* __restrict__ cur2, int gg,
        int* __restrict__ row_beg, int* __restrict__ row_cnt) {
    __shared__ int cnt[256];
    __shared__ int loc[GROUP];
    __shared__ int curs[GROUP];
    __shared__ int sorted[ST2CAP];
    const int tid = threadIdx.x;
    const int n = cur2[gg];
    int* s = st2 + (size_t)gg * ST2CAP;
    cnt[tid] = 0;
    __syncthreads();
    for (int i = tid; i < n; i += 256) atomicAdd(&cnt[s[i] >> SHIFT], 1);
    __syncthreads();
    const int x = cnt[tid];
    for (int d = 1; d < 256; d <<= 1) {
        const int v = (tid >= d) ? cnt[tid - d] : 0;
        __syncthreads();
        cnt[tid] += v;
        __syncthreads();
    }
    const int excl = cnt[tid] - x;
    if (tid < GROUP) { loc[tid] = excl; curs[tid] = excl; }
    __syncthreads();
    for (int i = tid; i < n; i += 256) {
        const int e = s[i];
        const int pos = atomicAdd(&curs[e >> SHIFT], 1);
        sorted[pos] = e;
    }
    __syncthreads();
    for (int i = tid; i < n; i += 256) s[i] = sorted[i];
    if (tid < GROUP) {
        row_beg[gg * GROUP + tid] = gg * ST2CAP + loc[tid];
        row_cnt[gg * GROUP + tid] = x;
    }
}

// Fused: blocks [0,800) entity; [800,1200) mat-col; [1200,1600) mat-row.
__global__ __launch_bounds__(256) void sort_all(
        int* __restrict__ st2_e, const int* __restrict__ cur2_e,
        int* __restrict__ beg_e, int* __restrict__ cnt_e,
        int* __restrict__ stC2, const int* __restrict__ cur2_c,
        int* __restrict__ beg_c, int* __restrict__ cnt_c,
        int* __restrict__ stR2, const int* __restrict__ cur2_r,
        int* __restrict__ beg_r, int* __restrict__ cnt_r) {
    const int b = blockIdx.x;
    if (b < 800)       group_sort_body<22>(st2_e, cur2_e, b, beg_e, cnt_e);
    else if (b < 1200) group_sort_body<16>(stC2, cur2_c, b - 800, beg_c, cnt_c);
    else               group_sort_body<16>(stR2, cur2_r, b - 1200, beg_r, cnt_r);
}

// ---------------------------------------------------------------------------
// Fused pull (r14 structure, proven). ROUND-16 CHANGE: weight staged in LDS —
// entity branch's wgt gather moves from global VMEM to the LGKM pipe, halving
// per-edge VMEM instructions. Index math and MASKS unchanged (r9-11 lesson).
// ---------------------------------------------------------------------------
__global__ void pull_ei_kernel(
        const float* __restrict__ ent, const float* __restrict__ wgt,
        const int* __restrict__ beg_e, const int* __restrict__ cnt_e,
        const int* __restrict__ ids_e, float* __restrict__ out_e,
        const float* __restrict__ uemb,
        const int* __restrict__ beg_c, const int* __restrict__ cnt_c,
        const int* __restrict__ ids_c, float* __restrict__ iu_out) {
    __shared__ float WS[32 * DD];    // weight table, 8 KB
    const int tid = threadIdx.x;
    for (int i = tid; i < 32 * DD; i += 256) WS[i] = wgt[i];
    __syncthreads();

    const int lane = tid & 63;
    if (blockIdx.x < 25000) {
        const int wid = (blockIdx.x * 256 + tid) >> 6;
        const int beg = beg_e[wid], nc = cnt_e[wid];
        const int end = beg + nc;
        float acc = 0.f;
        for (int base = beg; base < end; base += 64) {
            const int k = base + lane;
            int v = 0;
            if (k < end) v = ids_e[k];
            const int nn = min(64, end - base);
            int kk = 0;
            for (; kk + 4 <= nn; kk += 4) {
                const int v0 = __shfl(v, kk),     v1 = __shfl(v, kk + 1);
                const int v2 = __shfl(v, kk + 2), v3 = __shfl(v, kk + 3);
                const float a0 = ent[(size_t)(v0 & 0x1FFFF) * DD + lane] * WS[((v0 >> 17) & 31) * DD + lane];
                const float a1 = ent[(size_t)(v1 & 0x1FFFF) * DD + lane] * WS[((v1 >> 17) & 31) * DD + lane];
                const float a2 = ent[(size_t)(v2 & 0x1FFFF) * DD + lane] * WS[((v2 >> 17) & 31) * DD + lane];
                const float a3 = ent[(size_t)(v3 & 0x1FFFF) * DD + lane] * WS[((v3 >> 17) & 31) * DD + lane];
                acc += a0 + a1 + a2 + a3;
            }
            for (; kk < nn; ++kk) {
                const int vv = __shfl(v, kk);
                acc += ent[(size_t)(vv & 0x1FFFF) * DD + lane] * WS[((vv >> 17) & 31) * DD + lane];
            }
        }
        out_e[(size_t)wid * DD + lane] = acc / fmaxf((float)nc, 1.0f);
    } else {
        const int wid = ((blockIdx.x - 25000) * 256 + tid) >> 6;
        if (wid >= N_ITEMS) return;
        const float w0 = WS[lane];   // weight[0][lane]
        const int beg = beg_c[wid], nc = cnt_c[wid];
        const int end = beg + nc;
        float acc = 0.f;
        for (int base = beg; base < end; base += 64) {
            const int k = base + lane;
            int v = 0;
            if (k < end) v = ids_c[k];
            const int nn = min(64, end - base);
            int kk = 0;
            for (; kk + 4 <= nn; kk += 4) {
                const int v0 = __shfl(v, kk),     v1 = __shfl(v, kk + 1);
                const int v2 = __shfl(v, kk + 2), v3 = __shfl(v, kk + 3);
                acc += uemb[(size_t)(v0 & 0xFFFF) * DD + lane] + uemb[(size_t)(v1 & 0xFFFF) * DD + lane]
                     + uemb[(size_t)(v2 & 0xFFFF) * DD + lane] + uemb[(size_t)(v3 & 0xFFFF) * DD + lane];
            }
            for (; kk < nn; ++kk) {
                const int vv = __shfl(v, kk);
                acc += uemb[(size_t)(vv & 0xFFFF) * DD + lane];
            }
        }
        iu_out[(size_t)wid * DD + lane] = acc * w0 / fmaxf((float)nc, 1.0f);
    }
}

__global__ void pull_user_kernel(const float* __restrict__ fus,
                                 const int* __restrict__ row_beg,
                                 const int* __restrict__ row_cnt,
                                 const int* __restrict__ ids,
                                 float* __restrict__ uout) {
    const int lane = threadIdx.x & 63;
    const int wid = (blockIdx.x * blockDim.x + threadIdx.x) >> 6;
    if (wid >= N_USERS) return;
    const int beg = row_beg[wid], nc = row_cnt[wid];
    const int end = beg + nc;
    float acc = 0.f;
    for (int base = beg; base < end; base += 64) {
        const int k = base + lane;
        int v = 0;
        if (k < end) v = ids[k];
        const int nn = min(64, end - base);
        int kk = 0;
        for (; kk + 4 <= nn; kk += 4) {
            const int v0 = __shfl(v, kk),     v1 = __shfl(v, kk + 1);
            const int v2 = __shfl(v, kk + 2), v3 = __shfl(v, kk + 3);
            acc += fus[(size_t)(v0 & 0xFFFF) * DD + lane] + fus[(size_t)(v1 & 0xFFFF) * DD + lane]
                 + fus[(size_t)(v2 & 0xFFFF) * DD + lane] + fus[(size_t)(v3 & 0xFFFF) * DD + lane];
        }
        for (; kk < nn; ++kk) {
            const int vv = __shfl(v, kk);
            acc += fus[(size_t)(vv & 0xFFFF) * DD + lane];
        }
    }
    uout[(size_t)wid * DD + lane] = acc;
}

// ---------------------------------------------------------------------------
// Gate + fusion, in place on d_out. 32 items per block (G1/G2 staged once).
// ---------------------------------------------------------------------------
__global__ __launch_bounds__(256) void gate_fusion_kernel(
        float* __restrict__ kg_fus, const float* __restrict__ iu,
        const float* __restrict__ g1, const float* __restrict__ g2) {
    __shared__ float G1[64 * 65];
    __shared__ float G2[64 * 65];
    __shared__ float xs1[4][64];
    __shared__ float xs2[4][64];

    const int tid = threadIdx.x;
    for (int i = tid; i < 64 * 64; i += 256) {
        const int r = i >> 6, c = i & 63;
        G1[r * 65 + c] = g1[i];
        G2[r * 65 + c] = g2[i];
    }
    const int il = tid >> 6;
    const int j = tid & 63;
    const int base = blockIdx.x * 32;
    __syncthreads();

    for (int it = 0; it < 8; ++it) {
        const int item = base + it * 4 + il;
        const bool ok = item < N_ITEMS;
        float x1 = 0.f, x2 = 0.f;
        if (ok) {
            x1 = kg_fus[(size_t)item * DD + j];
            x2 = iu[(size_t)item * DD + j];
        }
        xs1[il][j] = x1;
        xs2[il][j] = x2;
        __syncthreads();
        float s = 0.0f;
        #pragma unroll
        for (int k = 0; k < 64; ++k) {
            s += xs1[il][k] * G1[j * 65 + k];
            s += xs2[il][k] * G2[j * 65 + k];
        }
        const float gi = 1.0f / (1.0f + __expf(-s));
        if (ok) kg_fus[(size_t)item * DD + j] = gi * x1 + (1.0f - gi) * x2;
        __syncthreads();
    }
}

extern "C" void kernel_launch(void* const* d_in, const int* in_sizes, int n_in,
                              void* d_out, int out_size, void* d_ws, size_t ws_size,
                              hipStream_t stream) {
    const float* entity_emb = (const float*)d_in[0];
    const float* user_emb   = (const float*)d_in[1];
    const int*   edge_index = (const int*)d_in[2];
    const int*   edge_type  = (const int*)d_in[3];
    const int*   mat_row    = (const int*)d_in[4];
    const int*   mat_col    = (const int*)d_in[5];
    const float* weight     = (const float*)d_in[7];
    const float* gate1_w    = (const float*)d_in[8];
    const float* gate2_w    = (const float*)d_in[9];

    float* out = (float*)d_out;
    float* out_fusion = out;                       // rows [0, 50000)
    float* out_entity = out;                       // rows [0, 100000)
    float* out_user   = out + (size_t)N_ENT * DD;  // temp i_u_agg, then user_agg

    // workspace (ints), peak 32.2 MB. Stream-ordered aliasing:
    //   st_ek/st_ev dead after bucket_edge_L2 -> stC,stR overlay st_ek region,
    //   stC2 overlays st_ev region. st2_e / stR2 / tabs are fresh.
    int* W      = (int*)d_ws;
    int* cur_e  = W + 0;         // 8
    int* cur_c  = W + 8;         // 8
    int* cur_r  = W + 16;        // 8
    int* cur2_e = W + 24;        // 800
    int* cur2_c = W + 824;       // 400
    int* cur2_r = W + 1224;      // 400   (cursors end 1624, pad to 2048)
    int* st_ek  = W + 2048;                    // 2,097,152
    int* st_ev  = st_ek + 2097152;             // 2,097,152
    int* stC    = st_ek;                       // 1,048,576 (aliases st_ek)
    int* stR    = st_ek + 1048576;             // 1,048,576 (aliases st_ek)
    int* stC2   = st_ev;                       // 1,152,000 (aliases st_ev)
    int* st2_e  = st_ev + 2097152;             // 800*2880 = 2,304,000 (fresh)
    int* stR2   = st2_e + 2304000;             // 1,152,000 (fresh)
    int* tabs   = stR2 + 1152000;              // 400,000
    int* beg_e  = tabs;            // 100,000
    int* cnt_e  = tabs + 100000;   // 100,000
    int* beg_c  = tabs + 200000;   // 50,000
    int* cnt_c  = tabs + 250000;   // 50,000
    int* beg_r  = tabs + 300000;   // 50,000
    int* cnt_r  = tabs + 350000;   // 50,000  (end = 8,052,352 ints = 32.2 MB)

    const int* head = edge_index;
    const int* tail = edge_index + NE;

    // 1. zero all cursors (8 KB)
    (void)hipMemsetAsync(W, 0, 2048 * sizeof(int), stream);

    // 2-3. edge chain build (st_ek/st_ev live)
    bucket_edge_L1<<<512, 256, 0, stream>>>(head, tail, edge_type, st_ek, st_ev, cur_e);
    bucket_edge_L2<<<256, 1024, 0, stream>>>(st_ek, st_ev, cur_e, st2_e, cur2_e);

    // 4-6. mat chain build (st_ek/st_ev dead; stC/stR/stC2 overlay them)
    bucket_mat_L1<<<256, 256, 0, stream>>>(mat_row, mat_col, stC, cur_c, stR, cur_r);
    bucket_mat_L2<<<256, 1024, 0, stream>>>(stC, cur_c, stC2, cur2_c);
    bucket_mat_L2<<<256, 1024, 0, stream>>>(stR, cur_r, stR2, cur2_r);

    // 7. all group sorts (entity + mat-col + mat-row)
    sort_all<<<1600, 256, 0, stream>>>(st2_e, cur2_e, beg_e, cnt_e,
                                       stC2, cur2_c, beg_c, cnt_c,
                                       stR2, cur2_r, beg_r, cnt_r);
    // 8. fused entity + i_u pulls (weight in LDS)
    pull_ei_kernel<<<37500, 256, 0, stream>>>(entity_emb, weight,
                                              beg_e, cnt_e, st2_e, out_entity,
                                              user_emb, beg_c, cnt_c, stC2, out_user);
    // 9. gate + fusion (in place on d_out item rows)
    gate_fusion_kernel<<<(N_ITEMS + 31) / 32, 256, 0, stream>>>(out_fusion, out_user,
                                                                gate1_w, gate2_w);
    // 10. user_agg
    pull_user_kernel<<<N_USERS / 4, 256, 0, stream>>>(out_fusion,
                                                      beg_r, cnt_r, stR2, out_user);
}

// Round 17
// 364.334 us; speedup vs baseline: 1.0350x; 1.0350x over previous
//
#include <hip/hip_runtime.h>
#include <hip/hip_bf16.h>

#define N_USERS   50000
#define N_ITEMS   50000
#define N_ENT     100000
#define NE        2000000
#define NNI       1000000
#define DD        64

#define PART_E    12500    // entity rows per XCD partition
#define PART_I    6250     // item/user rows per XCD partition
#define GROUP     125      // rows per sort group
#define NG_E      100      // groups per entity partition
#define NG_M      50       // groups per item/user partition

#define ECAP_E    262144   // per-XCD-bucket capacity, edges (mean 250000)
#define ECAP_M    131072   // per-XCD-bucket capacity, mat   (mean 125000)
#define ST2CAP    2880     // per-group capacity (mean 2500)
#define CHUNK     4096
#define CAPB      640      // L1 LDS per-bucket staging
#define GCAP      96       // L2 LDS per-group staging

// ---------------------------------------------------------------------------
// L1 bucket: edges -> 8 XCD-partition buckets (proven r12).
// val = tail | etype<<17.
// ---------------------------------------------------------------------------
__global__ __launch_bounds__(256) void bucket_edge_L1(
        const int* __restrict__ head, const int* __restrict__ tail,
        const int* __restrict__ etype,
        int* __restrict__ stK, int* __restrict__ stV, int* __restrict__ cur) {
    __shared__ int bufK[8][CAPB];
    __shared__ int bufV[8][CAPB];
    __shared__ int lcnt[8];
    __shared__ int gbase[8];
    const int tid = threadIdx.x;
    const int lane = tid & 63;
    for (int cs = blockIdx.x * CHUNK; cs < NE; cs += gridDim.x * CHUNK) {
        if (tid < 8) lcnt[tid] = 0;
        __syncthreads();
        const int ce = min(cs + CHUNK, NE);
        for (int i0 = cs; i0 < ce; i0 += 256) {
            const int i = i0 + tid;
            const bool valid = i < ce;
            int h = 0, v = 0, b = 8;
            if (valid) {
                h = __builtin_nontemporal_load(head + i);
                v = __builtin_nontemporal_load(tail + i) |
                    (__builtin_nontemporal_load(etype + i) << 17);
                b = h / PART_E;
            }
            unsigned long long m[8];
            #pragma unroll
            for (int k = 0; k < 8; ++k) m[k] = __ballot(b == k);
            int base8 = 0;
            if (lane < 8) base8 = atomicAdd(&lcnt[lane], (int)__popcll(m[lane]));
            if (valid) {
                const int mybase = __shfl(base8, b);
                const int pos = mybase + (int)__popcll(m[b] & ((1ull << lane) - 1ull));
                if (pos < CAPB) { bufK[b][pos] = h; bufV[b][pos] = v; }
                else {
                    const int gp = atomicAdd(&cur[b], 1);
                    stK[(size_t)b * ECAP_E + gp] = h;
                    stV[(size_t)b * ECAP_E + gp] = v;
                }
            }
        }
        __syncthreads();
        if (tid < 8) gbase[tid] = atomicAdd(&cur[tid], min(lcnt[tid], CAPB));
        __syncthreads();
        for (int b = 0; b < 8; ++b) {
            const int nf = min(lcnt[b], CAPB);
            int* dK = stK + (size_t)b * ECAP_E + gbase[b];
            int* dV = stV + (size_t)b * ECAP_E + gbase[b];
            for (int j = tid; j < nf; j += 256) { dK[j] = bufK[b][j]; dV[j] = bufV[b][j]; }
        }
        __syncthreads();
    }
}

// ---------------------------------------------------------------------------
// L1 bucket: mat entries both directions, packed (key<<16)|other. (proven r12)
// ---------------------------------------------------------------------------
__global__ __launch_bounds__(256) void bucket_mat_L1(
        const int* __restrict__ mrow, const int* __restrict__ mcol,
        int* __restrict__ stC, int* __restrict__ curC,
        int* __restrict__ stR, int* __restrict__ curR) {
    __shared__ int bufc[8][CAPB];
    __shared__ int bufr[8][CAPB];
    __shared__ int lc[8], lr[8], gc[8], gr[8];
    const int tid = threadIdx.x;
    const int lane = tid & 63;
    for (int cs = blockIdx.x * CHUNK; cs < NNI; cs += gridDim.x * CHUNK) {
        if (tid < 8) { lc[tid] = 0; lr[tid] = 0; }
        __syncthreads();
        const int ce = min(cs + CHUNK, NNI);
        for (int i0 = cs; i0 < ce; i0 += 256) {
            const int i = i0 + tid;
            const bool valid = i < ce;
            int r = 0, c = 0, bc = 8, br = 8;
            if (valid) {
                r = __builtin_nontemporal_load(mrow + i);
                c = __builtin_nontemporal_load(mcol + i);
                bc = c / PART_I;
                br = r / PART_I;
            }
            unsigned long long mc[8], mrr[8];
            #pragma unroll
            for (int k = 0; k < 8; ++k) { mc[k] = __ballot(bc == k); mrr[k] = __ballot(br == k); }
            int bc8 = 0, br8 = 0;
            if (lane < 8) {
                bc8 = atomicAdd(&lc[lane], (int)__popcll(mc[lane]));
                br8 = atomicAdd(&lr[lane], (int)__popcll(mrr[lane]));
            }
            if (valid) {
                const unsigned long long lt = (1ull << lane) - 1ull;
                int pos = __shfl(bc8, bc) + (int)__popcll(mc[bc] & lt);
                const int vc = (int)(((unsigned)c << 16) | (unsigned)r);
                if (pos < CAPB) bufc[bc][pos] = vc;
                else stC[(size_t)bc * ECAP_M + atomicAdd(&curC[bc], 1)] = vc;
                pos = __shfl(br8, br) + (int)__popcll(mrr[br] & lt);
                const int vr = (int)(((unsigned)r << 16) | (unsigned)c);
                if (pos < CAPB) bufr[br][pos] = vr;
                else stR[(size_t)br * ECAP_M + atomicAdd(&curR[br], 1)] = vr;
            }
        }
        __syncthreads();
        if (tid < 8)       gc[tid]     = atomicAdd(&curC[tid],     min(lc[tid],     CAPB));
        else if (tid < 16) gr[tid - 8] = atomicAdd(&curR[tid - 8], min(lr[tid - 8], CAPB));
        __syncthreads();
        for (int b = 0; b < 8; ++b) {
            int nf = min(lc[b], CAPB);
            int* d = stC + (size_t)b * ECAP_M + gc[b];
            for (int j = tid; j < nf; j += 256) d[j] = bufc[b][j];
            nf = min(lr[b], CAPB);
            d = stR + (size_t)b * ECAP_M + gr[b];
            for (int j = tid; j < nf; j += 256) d[j] = bufr[b][j];
        }
        __syncthreads();
    }
}

// ---------------------------------------------------------------------------
// L2 bucket edges: partition -> 125-row groups. entry: val | rig<<22.
// 1024 threads (proven r12).
// ---------------------------------------------------------------------------
__global__ __launch_bounds__(1024) void bucket_edge_L2(
        const int* __restrict__ stK, const int* __restrict__ stV,
        const int* __restrict__ cur, int* __restrict__ st2,
        int* __restrict__ cur2) {
    __shared__ int buf[NG_E][GCAP];
    __shared__ int lcnt[NG_E];
    const int p = blockIdx.x & 7;
    const int nb = gridDim.x >> 3;
    const int bi = blockIdx.x >> 3;
    const int n = cur[p];
    const int tid = threadIdx.x, w = tid >> 6, lane = tid & 63;
    const int* sK = stK + (size_t)p * ECAP_E;
    const int* sV = stV + (size_t)p * ECAP_E;
    const int pbase = p * PART_E;
    int* cur2p = cur2 + p * NG_E;
    for (int cs = bi * CHUNK; cs < n; cs += nb * CHUNK) {
        for (int t = tid; t < NG_E; t += 1024) lcnt[t] = 0;
        __syncthreads();
        const int ce = min(cs + CHUNK, n);
        for (int i = cs + tid; i < ce; i += 1024) {
            const int local = __builtin_nontemporal_load(sK + i) - pbase;
            const int g = local / GROUP;
            const int rig = local - g * GROUP;
            const int entry = __builtin_nontemporal_load(sV + i) | (rig << 22);
            const int pos = atomicAdd(&lcnt[g], 1);
            if (pos < GCAP) buf[g][pos] = entry;
            else st2[(size_t)(p * NG_E + g) * ST2CAP + atomicAdd(&cur2p[g], 1)] = entry;
        }
        __syncthreads();
        for (int gi = w; gi < NG_E; gi += 16) {
            const int nf = min(lcnt[gi], GCAP);
            int base = 0;
            if (lane == 0 && nf > 0) base = atomicAdd(&cur2p[gi], nf);
            base = __shfl(base, 0);
            int* d = st2 + (size_t)(p * NG_E + gi) * ST2CAP + base;
            for (int j = lane; j < nf; j += 64) d[j] = buf[gi][j];
        }
        __syncthreads();
    }
}

// mat entry: other | rig<<16.  (proven r12, 1024 threads, separate launches)
__global__ __launch_bounds__(1024) void bucket_mat_L2(
        const int* __restrict__ st, const int* __restrict__ cur8,
        int* __restrict__ st2, int* __restrict__ cur2) {
    __shared__ int buf[NG_M][GCAP];
    __shared__ int lcnt[NG_M];
    const int p = blockIdx.x & 7;
    const int nb = gridDim.x >> 3;
    const int bi = blockIdx.x >> 3;
    const int n = cur8[p];
    const int tid = threadIdx.x, w = tid >> 6, lane = tid & 63;
    const int* s = st + (size_t)p * ECAP_M;
    const int pbase = p * PART_I;
    int* cur2p = cur2 + p * NG_M;
    for (int cs = bi * CHUNK; cs < n; cs += nb * CHUNK) {
        for (int t = tid; t < NG_M; t += 1024) lcnt[t] = 0;
        __syncthreads();
        const int ce = min(cs + CHUNK, n);
        for (int i = cs + tid; i < ce; i += 1024) {
            const unsigned u = (unsigned)__builtin_nontemporal_load(s + i);
            const int local = (int)(u >> 16) - pbase;
            const int g = local / GROUP;
            const int rig = local - g * GROUP;
            const int entry = (int)(u & 0xFFFFu) | (rig << 16);
            const int pos = atomicAdd(&lcnt[g], 1);
            if (pos < GCAP) buf[g][pos] = entry;
            else st2[(size_t)(p * NG_M + g) * ST2CAP + atomicAdd(&cur2p[g], 1)] = entry;
        }
        __syncthreads();
        for (int gi = w; gi < NG_M; gi += 16) {
            const int nf = min(lcnt[gi], GCAP);
            int base = 0;
            if (lane == 0 && nf > 0) base = atomicAdd(&cur2p[gi], nf);
            base = __shfl(base, 0);
            int* d = st2 + (size_t)(p * NG_M + gi) * ST2CAP + base;
            for (int j = lane; j < nf; j += 64) d[j] = buf[gi][j];
        }
        __syncthreads();
    }
}

// ---------------------------------------------------------------------------
// Group-local LDS counting sort (proven). Entries retain rig bits.
// ---------------------------------------------------------------------------
template <int SHIFT>
__device__ __forceinline__ void group_sort_body(
        int* __restrict__ st2, const int* __restrict__ cur2, int gg,
        int* __restrict__ row_beg, int* __restrict__ row_cnt) {
    __shared__ int cnt[256];
    __shared__ int loc[GROUP];
    __shared__ int curs[GROUP];
    __shared__ int sorted[ST2CAP];
    const int tid = threadIdx.x;
    const int n = cur2[gg];
    int* s = st2 + (size_t)gg * ST2CAP;
    cnt[tid] = 0;
    __syncthreads();
    for (int i = tid; i < n; i += 256) atomicAdd(&cnt[s[i] >> SHIFT], 1);
    __syncthreads();
    const int x = cnt[tid];
    for (int d = 1; d < 256; d <<= 1) {
        const int v = (tid >= d) ? cnt[tid - d] : 0;
        __syncthreads();
        cnt[tid] += v;
        __syncthreads();
    }
    const int excl = cnt[tid] - x;
    if (tid < GROUP) { loc[tid] = excl; curs[tid] = excl; }
    __syncthreads();
    for (int i = tid; i < n; i += 256) {
        const int e = s[i];
        const int pos = atomicAdd(&curs[e >> SHIFT], 1);
        sorted[pos] = e;
    }
    __syncthreads();
    for (int i = tid; i < n; i += 256) s[i] = sorted[i];
    if (tid < GROUP) {
        row_beg[gg * GROUP + tid] = gg * ST2CAP + loc[tid];
        row_cnt[gg * GROUP + tid] = x;
    }
}

// Fused: blocks [0,800) entity; [800,1200) mat-col; [1200,1600) mat-row.
__global__ __launch_bounds__(256) void sort_all(
        int* __restrict__ st2_e, const int* __restrict__ cur2_e,
        int* __restrict__ beg_e, int* __restrict__ cnt_e,
        int* __restrict__ stC2, const int* __restrict__ cur2_c,
        int* __restrict__ beg_c, int* __restrict__ cnt_c,
        int* __restrict__ stR2, const int* __restrict__ cur2_r,
        int* __restrict__ beg_r, int* __restrict__ cnt_r) {
    const int b = blockIdx.x;
    if (b < 800)       group_sort_body<22>(st2_e, cur2_e, b, beg_e, cnt_e);
    else if (b < 1200) group_sort_body<16>(stC2, cur2_c, b - 800, beg_c, cnt_c);
    else               group_sort_body<16>(stR2, cur2_r, b - 1200, beg_r, cnt_r);
}

// ---------------------------------------------------------------------------
// Fused pull (r14 structure, proven; wgt via global/L1 — r16 showed LDS
// staging hurts). ROUND-17 CHANGE: nontemporal loads on the streamed ids
// arrays so they don't evict gather-reused table lines from L2.
// MASKS REQUIRED (r9-11 faults were a dropped mask).
// ---------------------------------------------------------------------------
__global__ void pull_ei_kernel(
        const float* __restrict__ ent, const float* __restrict__ wgt,
        const int* __restrict__ beg_e, const int* __restrict__ cnt_e,
        const int* __restrict__ ids_e, float* __restrict__ out_e,
        const float* __restrict__ uemb,
        const int* __restrict__ beg_c, const int* __restrict__ cnt_c,
        const int* __restrict__ ids_c, float* __restrict__ iu_out) {
    const int lane = threadIdx.x & 63;
    if (blockIdx.x < 25000) {
        const int wid = (blockIdx.x * 256 + threadIdx.x) >> 6;
        const int beg = beg_e[wid], nc = cnt_e[wid];
        const int end = beg + nc;
        float acc = 0.f;
        for (int base = beg; base < end; base += 64) {
            const int k = base + lane;
            int v = 0;
            if (k < end) v = __builtin_nontemporal_load(ids_e + k);
            const int nn = min(64, end - base);
            int kk = 0;
            for (; kk + 4 <= nn; kk += 4) {
                const int v0 = __shfl(v, kk),     v1 = __shfl(v, kk + 1);
                const int v2 = __shfl(v, kk + 2), v3 = __shfl(v, kk + 3);
                const float a0 = ent[(size_t)(v0 & 0x1FFFF) * DD + lane] * wgt[((v0 >> 17) & 31) * DD + lane];
                const float a1 = ent[(size_t)(v1 & 0x1FFFF) * DD + lane] * wgt[((v1 >> 17) & 31) * DD + lane];
                const float a2 = ent[(size_t)(v2 & 0x1FFFF) * DD + lane] * wgt[((v2 >> 17) & 31) * DD + lane];
                const float a3 = ent[(size_t)(v3 & 0x1FFFF) * DD + lane] * wgt[((v3 >> 17) & 31) * DD + lane];
                acc += a0 + a1 + a2 + a3;
            }
            for (; kk < nn; ++kk) {
                const int vv = __shfl(v, kk);
                acc += ent[(size_t)(vv & 0x1FFFF) * DD + lane] * wgt[((vv >> 17) & 31) * DD + lane];
            }
        }
        out_e[(size_t)wid * DD + lane] = acc / fmaxf((float)nc, 1.0f);
    } else {
        const int wid = ((blockIdx.x - 25000) * 256 + threadIdx.x) >> 6;
        if (wid >= N_ITEMS) return;
        const float w0 = wgt[lane];
        const int beg = beg_c[wid], nc = cnt_c[wid];
        const int end = beg + nc;
        float acc = 0.f;
        for (int base = beg; base < end; base += 64) {
            const int k = base + lane;
            int v = 0;
            if (k < end) v = __builtin_nontemporal_load(ids_c + k);
            const int nn = min(64, end - base);
            int kk = 0;
            for (; kk + 4 <= nn; kk += 4) {
                const int v0 = __shfl(v, kk),     v1 = __shfl(v, kk + 1);
                const int v2 = __shfl(v, kk + 2), v3 = __shfl(v, kk + 3);
                acc += uemb[(size_t)(v0 & 0xFFFF) * DD + lane] + uemb[(size_t)(v1 & 0xFFFF) * DD + lane]
                     + uemb[(size_t)(v2 & 0xFFFF) * DD + lane] + uemb[(size_t)(v3 & 0xFFFF) * DD + lane];
            }
            for (; kk < nn; ++kk) {
                const int vv = __shfl(v, kk);
                acc += uemb[(size_t)(vv & 0xFFFF) * DD + lane];
            }
        }
        iu_out[(size_t)wid * DD + lane] = acc * w0 / fmaxf((float)nc, 1.0f);
    }
}

__global__ void pull_user_kernel(const float* __restrict__ fus,
                                 const int* __restrict__ row_beg,
                                 const int* __restrict__ row_cnt,
                                 const int* __restrict__ ids,
                                 float* __restrict__ uout) {
    const int lane = threadIdx.x & 63;
    const int wid = (blockIdx.x * blockDim.x + threadIdx.x) >> 6;
    if (wid >= N_USERS) return;
    const int beg = row_beg[wid], nc = row_cnt[wid];
    const int end = beg + nc;
    float acc = 0.f;
    for (int base = beg; base < end; base += 64) {
        const int k = base + lane;
        int v = 0;
        if (k < end) v = __builtin_nontemporal_load(ids + k);
        const int nn = min(64, end - base);
        int kk = 0;
        for (; kk + 4 <= nn; kk += 4) {
            const int v0 = __shfl(v, kk),     v1 = __shfl(v, kk + 1);
            const int v2 = __shfl(v, kk + 2), v3 = __shfl(v, kk + 3);
            acc += fus[(size_t)(v0 & 0xFFFF) * DD + lane] + fus[(size_t)(v1 & 0xFFFF) * DD + lane]
                 + fus[(size_t)(v2 & 0xFFFF) * DD + lane] + fus[(size_t)(v3 & 0xFFFF) * DD + lane];
        }
        for (; kk < nn; ++kk) {
            const int vv = __shfl(v, kk);
            acc += fus[(size_t)(vv & 0xFFFF) * DD + lane];
        }
    }
    uout[(size_t)wid * DD + lane] = acc;
}

// ---------------------------------------------------------------------------
// Gate + fusion, in place on d_out. 32 items per block (G1/G2 staged once).
// ---------------------------------------------------------------------------
__global__ __launch_bounds__(256) void gate_fusion_kernel(
        float* __restrict__ kg_fus, const float* __restrict__ iu,
        const float* __restrict__ g1, const float* __restrict__ g2) {
    __shared__ float G1[64 * 65];
    __shared__ float G2[64 * 65];
    __shared__ float xs1[4][64];
    __shared__ float xs2[4][64];

    const int tid = threadIdx.x;
    for (int i = tid; i < 64 * 64; i += 256) {
        const int r = i >> 6, c = i & 63;
        G1[r * 65 + c] = g1[i];
        G2[r * 65 + c] = g2[i];
    }
    const int il = tid >> 6;
    const int j = tid & 63;
    const int base = blockIdx.x * 32;
    __syncthreads();

    for (int it = 0; it < 8; ++it) {
        const int item = base + it * 4 + il;
        const bool ok = item < N_ITEMS;
        float x1 = 0.f, x2 = 0.f;
        if (ok) {
            x1 = kg_fus[(size_t)item * DD + j];
            x2 = iu[(size_t)item * DD + j];
        }
        xs1[il][j] = x1;
        xs2[il][j] = x2;
        __syncthreads();
        float s = 0.0f;
        #pragma unroll
        for (int k = 0; k < 64; ++k) {
            s += xs1[il][k] * G1[j * 65 + k];
            s += xs2[il][k] * G2[j * 65 + k];
        }
        const float gi = 1.0f / (1.0f + __expf(-s));
        if (ok) kg_fus[(size_t)item * DD + j] = gi * x1 + (1.0f - gi) * x2;
        __syncthreads();
    }
}

extern "C" void kernel_launch(void* const* d_in, const int* in_sizes, int n_in,
                              void* d_out, int out_size, void* d_ws, size_t ws_size,
                              hipStream_t stream) {
    const float* entity_emb = (const float*)d_in[0];
    const float* user_emb   = (const float*)d_in[1];
    const int*   edge_index = (const int*)d_in[2];
    const int*   edge_type  = (const int*)d_in[3];
    const int*   mat_row    = (const int*)d_in[4];
    const int*   mat_col    = (const int*)d_in[5];
    const float* weight     = (const float*)d_in[7];
    const float* gate1_w    = (const float*)d_in[8];
    const float* gate2_w    = (const float*)d_in[9];

    float* out = (float*)d_out;
    float* out_fusion = out;                       // rows [0, 50000)
    float* out_entity = out;                       // rows [0, 100000)
    float* out_user   = out + (size_t)N_ENT * DD;  // temp i_u_agg, then user_agg

    // workspace (ints), peak 32.2 MB. Stream-ordered aliasing:
    //   st_ek/st_ev dead after bucket_edge_L2 -> stC,stR overlay st_ek region,
    //   stC2 overlays st_ev region. st2_e / stR2 / tabs are fresh.
    int* W      = (int*)d_ws;
    int* cur_e  = W + 0;         // 8
    int* cur_c  = W + 8;         // 8
    int* cur_r  = W + 16;        // 8
    int* cur2_e = W + 24;        // 800
    int* cur2_c = W + 824;       // 400
    int* cur2_r = W + 1224;      // 400   (cursors end 1624, pad to 2048)
    int* st_ek  = W + 2048;                    // 2,097,152
    int* st_ev  = st_ek + 2097152;             // 2,097,152
    int* stC    = st_ek;                       // 1,048,576 (aliases st_ek)
    int* stR    = st_ek + 1048576;             // 1,048,576 (aliases st_ek)
    int* stC2   = st_ev;                       // 1,152,000 (aliases st_ev)
    int* st2_e  = st_ev + 2097152;             // 800*2880 = 2,304,000 (fresh)
    int* stR2   = st2_e + 2304000;             // 1,152,000 (fresh)
    int* tabs   = stR2 + 1152000;              // 400,000
    int* beg_e  = tabs;            // 100,000
    int* cnt_e  = tabs + 100000;   // 100,000
    int* beg_c  = tabs + 200000;   // 50,000
    int* cnt_c  = tabs + 250000;   // 50,000
    int* beg_r  = tabs + 300000;   // 50,000
    int* cnt_r  = tabs + 350000;   // 50,000  (end = 8,052,352 ints = 32.2 MB)

    const int* head = edge_index;
    const int* tail = edge_index + NE;

    // 1. zero all cursors (8 KB)
    (void)hipMemsetAsync(W, 0, 2048 * sizeof(int), stream);

    // 2-3. edge chain build (st_ek/st_ev live)
    bucket_edge_L1<<<512, 256, 0, stream>>>(head, tail, edge_type, st_ek, st_ev, cur_e);
    bucket_edge_L2<<<256, 1024, 0, stream>>>(st_ek, st_ev, cur_e, st2_e, cur2_e);

    // 4-6. mat chain build (st_ek/st_ev dead; stC/stR/stC2 overlay them)
    bucket_mat_L1<<<256, 256, 0, stream>>>(mat_row, mat_col, stC, cur_c, stR, cur_r);
    bucket_mat_L2<<<256, 1024, 0, stream>>>(stC, cur_c, stC2, cur2_c);
    bucket_mat_L2<<<256, 1024, 0, stream>>>(stR, cur_r, stR2, cur2_r);

    // 7. all group sorts (entity + mat-col + mat-row)
    sort_all<<<1600, 256, 0, stream>>>(st2_e, cur2_e, beg_e, cnt_e,
                                       stC2, cur2_c, beg_c, cnt_c,
                                       stR2, cur2_r, beg_r, cnt_r);
    // 8. fused entity + i_u pulls
    pull_ei_kernel<<<37500, 256, 0, stream>>>(entity_emb, weight,
                                              beg_e, cnt_e, st2_e, out_entity,
                                              user_emb, beg_c, cnt_c, stC2, out_user);
    // 9. gate + fusion (in place on d_out item rows)
    gate_fusion_kernel<<<(N_ITEMS + 31) / 32, 256, 0, stream>>>(out_fusion, out_user,
                                                                gate1_w, gate2_w);
    // 10. user_agg
    pull_user_kernel<<<N_USERS / 4, 256, 0, stream>>>(out_fusion,
                                                      beg_r, cnt_r, stR2, out_user);
}

// Round 18
// 352.751 us; speedup vs baseline: 1.0690x; 1.0328x over previous
//
#include <hip/hip_runtime.h>
#include <hip/hip_bf16.h>

#define N_USERS   50000
#define N_ITEMS   50000
#define N_ENT     100000
#define NE        2000000
#define NNI       1000000
#define DD        64

#define PART_E    12500    // entity rows per XCD partition
#define PART_I    6250     // item/user rows per XCD partition
#define GROUP     125      // rows per sort group
#define NG_E      100      // groups per entity partition
#define NG_M      50       // groups per item/user partition

#define ECAP_E    262144   // per-XCD-bucket capacity, edges (mean 250000)
#define ECAP_M    131072   // per-XCD-bucket capacity, mat   (mean 125000)
#define ST2CAP    2880     // per-group capacity (mean 2500)
#define CHUNK     4096
#define CAPB      640      // L1 LDS per-bucket staging
#define GCAP      96       // L2 LDS per-group staging

// ---------------------------------------------------------------------------
// Fused L1 bucketing: blocks [0,512) = edge chain, [512,768) = mat chain.
// Bodies byte-identical to the proven r12/r17 kernels; they touch disjoint
// buffers, so fusing only removes a serial dispatch.
// edge val = tail | etype<<17;  mat entry = (key<<16)|other.
// ---------------------------------------------------------------------------
__global__ __launch_bounds__(256) void bucket_L1_fused(
        const int* __restrict__ head, const int* __restrict__ tail,
        const int* __restrict__ etype,
        int* __restrict__ stK, int* __restrict__ stV, int* __restrict__ cur,
        const int* __restrict__ mrow, const int* __restrict__ mcol,
        int* __restrict__ stC, int* __restrict__ curC,
        int* __restrict__ stR, int* __restrict__ curR) {
    __shared__ int bufA[8][CAPB];
    __shared__ int bufB[8][CAPB];
    __shared__ int l1[8], l2[8], g1s[8], g2s[8];
    const int tid = threadIdx.x;
    const int lane = tid & 63;

    if (blockIdx.x < 512) {
        // ---------------- edge body (grid-equivalent 512) ----------------
        for (int cs = blockIdx.x * CHUNK; cs < NE; cs += 512 * CHUNK) {
            if (tid < 8) l1[tid] = 0;
            __syncthreads();
            const int ce = min(cs + CHUNK, NE);
            for (int i0 = cs; i0 < ce; i0 += 256) {
                const int i = i0 + tid;
                const bool valid = i < ce;
                int h = 0, v = 0, b = 8;
                if (valid) {
                    h = __builtin_nontemporal_load(head + i);
                    v = __builtin_nontemporal_load(tail + i) |
                        (__builtin_nontemporal_load(etype + i) << 17);
                    b = h / PART_E;
                }
                unsigned long long m[8];
                #pragma unroll
                for (int k = 0; k < 8; ++k) m[k] = __ballot(b == k);
                int base8 = 0;
                if (lane < 8) base8 = atomicAdd(&l1[lane], (int)__popcll(m[lane]));
                if (valid) {
                    const int mybase = __shfl(base8, b);
                    const int pos = mybase + (int)__popcll(m[b] & ((1ull << lane) - 1ull));
                    if (pos < CAPB) { bufA[b][pos] = h; bufB[b][pos] = v; }
                    else {
                        const int gp = atomicAdd(&cur[b], 1);
                        stK[(size_t)b * ECAP_E + gp] = h;
                        stV[(size_t)b * ECAP_E + gp] = v;
                    }
                }
            }
            __syncthreads();
            if (tid < 8) g1s[tid] = atomicAdd(&cur[tid], min(l1[tid], CAPB));
            __syncthreads();
            for (int b = 0; b < 8; ++b) {
                const int nf = min(l1[b], CAPB);
                int* dK = stK + (size_t)b * ECAP_E + g1s[b];
                int* dV = stV + (size_t)b * ECAP_E + g1s[b];
                for (int j = tid; j < nf; j += 256) { dK[j] = bufA[b][j]; dV[j] = bufB[b][j]; }
            }
            __syncthreads();
        }
    } else {
        // ---------------- mat body (grid-equivalent 256) ----------------
        const int mb = blockIdx.x - 512;
        for (int cs = mb * CHUNK; cs < NNI; cs += 256 * CHUNK) {
            if (tid < 8) { l1[tid] = 0; l2[tid] = 0; }
            __syncthreads();
            const int ce = min(cs + CHUNK, NNI);
            for (int i0 = cs; i0 < ce; i0 += 256) {
                const int i = i0 + tid;
                const bool valid = i < ce;
                int r = 0, c = 0, bc = 8, br = 8;
                if (valid) {
                    r = __builtin_nontemporal_load(mrow + i);
                    c = __builtin_nontemporal_load(mcol + i);
                    bc = c / PART_I;
                    br = r / PART_I;
                }
                unsigned long long mc[8], mrr[8];
                #pragma unroll
                for (int k = 0; k < 8; ++k) { mc[k] = __ballot(bc == k); mrr[k] = __ballot(br == k); }
                int bc8 = 0, br8 = 0;
                if (lane < 8) {
                    bc8 = atomicAdd(&l1[lane], (int)__popcll(mc[lane]));
                    br8 = atomicAdd(&l2[lane], (int)__popcll(mrr[lane]));
                }
                if (valid) {
                    const unsigned long long lt = (1ull << lane) - 1ull;
                    int pos = __shfl(bc8, bc) + (int)__popcll(mc[bc] & lt);
                    const int vc = (int)(((unsigned)c << 16) | (unsigned)r);
                    if (pos < CAPB) bufA[bc][pos] = vc;
                    else stC[(size_t)bc * ECAP_M + atomicAdd(&curC[bc], 1)] = vc;
                    pos = __shfl(br8, br) + (int)__popcll(mrr[br] & lt);
                    const int vr = (int)(((unsigned)r << 16) | (unsigned)c);
                    if (pos < CAPB) bufB[br][pos] = vr;
                    else stR[(size_t)br * ECAP_M + atomicAdd(&curR[br], 1)] = vr;
                }
            }
            __syncthreads();
            if (tid < 8)       g1s[tid]     = atomicAdd(&curC[tid],     min(l1[tid],     CAPB));
            else if (tid < 16) g2s[tid - 8] = atomicAdd(&curR[tid - 8], min(l2[tid - 8], CAPB));
            __syncthreads();
            for (int b = 0; b < 8; ++b) {
                int nf = min(l1[b], CAPB);
                int* d = stC + (size_t)b * ECAP_M + g1s[b];
                for (int j = tid; j < nf; j += 256) d[j] = bufA[b][j];
                nf = min(l2[b], CAPB);
                d = stR + (size_t)b * ECAP_M + g2s[b];
                for (int j = tid; j < nf; j += 256) d[j] = bufB[b][j];
            }
            __syncthreads();
        }
    }
}

// ---------------------------------------------------------------------------
// L2 bucket edges: partition -> 125-row groups. entry: val | rig<<22.
// 1024 threads (proven r12).
// ---------------------------------------------------------------------------
__global__ __launch_bounds__(1024) void bucket_edge_L2(
        const int* __restrict__ stK, const int* __restrict__ stV,
        const int* __restrict__ cur, int* __restrict__ st2,
        int* __restrict__ cur2) {
    __shared__ int buf[NG_E][GCAP];
    __shared__ int lcnt[NG_E];
    const int p = blockIdx.x & 7;
    const int nb = gridDim.x >> 3;
    const int bi = blockIdx.x >> 3;
    const int n = cur[p];
    const int tid = threadIdx.x, w = tid >> 6, lane = tid & 63;
    const int* sK = stK + (size_t)p * ECAP_E;
    const int* sV = stV + (size_t)p * ECAP_E;
    const int pbase = p * PART_E;
    int* cur2p = cur2 + p * NG_E;
    for (int cs = bi * CHUNK; cs < n; cs += nb * CHUNK) {
        for (int t = tid; t < NG_E; t += 1024) lcnt[t] = 0;
        __syncthreads();
        const int ce = min(cs + CHUNK, n);
        for (int i = cs + tid; i < ce; i += 1024) {
            const int local = __builtin_nontemporal_load(sK + i) - pbase;
            const int g = local / GROUP;
            const int rig = local - g * GROUP;
            const int entry = __builtin_nontemporal_load(sV + i) | (rig << 22);
            const int pos = atomicAdd(&lcnt[g], 1);
            if (pos < GCAP) buf[g][pos] = entry;
            else st2[(size_t)(p * NG_E + g) * ST2CAP + atomicAdd(&cur2p[g], 1)] = entry;
        }
        __syncthreads();
        for (int gi = w; gi < NG_E; gi += 16) {
            const int nf = min(lcnt[gi], GCAP);
            int base = 0;
            if (lane == 0 && nf > 0) base = atomicAdd(&cur2p[gi], nf);
            base = __shfl(base, 0);
            int* d = st2 + (size_t)(p * NG_E + gi) * ST2CAP + base;
            for (int j = lane; j < nf; j += 64) d[j] = buf[gi][j];
        }
        __syncthreads();
    }
}

// mat entry: other | rig<<16.  (proven r12, 1024 threads, separate launches)
__global__ __launch_bounds__(1024) void bucket_mat_L2(
        const int* __restrict__ st, const int* __restrict__ cur8,
        int* __restrict__ st2, int* __restrict__ cur2) {
    __shared__ int buf[NG_M][GCAP];
    __shared__ int lcnt[NG_M];
    const int p = blockIdx.x & 7;
    const int nb = gridDim.x >> 3;
    const int bi = blockIdx.x >> 3;
    const int n = cur8[p];
    const int tid = threadIdx.x, w = tid >> 6, lane = tid & 63;
    const int* s = st + (size_t)p * ECAP_M;
    const int pbase = p * PART_I;
    int* cur2p = cur2 + p * NG_M;
    for (int cs = bi * CHUNK; cs < n; cs += nb * CHUNK) {
        for (int t = tid; t < NG_M; t += 1024) lcnt[t] = 0;
        __syncthreads();
        const int ce = min(cs + CHUNK, n);
        for (int i = cs + tid; i < ce; i += 1024) {
            const unsigned u = (unsigned)__builtin_nontemporal_load(s + i);
            const int local = (int)(u >> 16) - pbase;
            const int g = local / GROUP;
            const int rig = local - g * GROUP;
            const int entry = (int)(u & 0xFFFFu) | (rig << 16);
            const int pos = atomicAdd(&lcnt[g], 1);
            if (pos < GCAP) buf[g][pos] = entry;
            else st2[(size_t)(p * NG_M + g) * ST2CAP + atomicAdd(&cur2p[g], 1)] = entry;
        }
        __syncthreads();
        for (int gi = w; gi < NG_M; gi += 16) {
            const int nf = min(lcnt[gi], GCAP);
            int base = 0;
            if (lane == 0 && nf > 0) base = atomicAdd(&cur2p[gi], nf);
            base = __shfl(base, 0);
            int* d = st2 + (size_t)(p * NG_M + gi) * ST2CAP + base;
            for (int j = lane; j < nf; j += 64) d[j] = buf[gi][j];
        }
        __syncthreads();
    }
}

// ---------------------------------------------------------------------------
// Group-local LDS counting sort (proven). Entries retain rig bits.
// ---------------------------------------------------------------------------
template <int SHIFT>
__device__ __forceinline__ void group_sort_body(
        int* __restrict__ st2, const int* __restrict__ cur2, int gg,
        int* __restrict__ row_beg, int* __restrict__ row_cnt) {
    __shared__ int cnt[256];
    __shared__ int loc[GROUP];
    __shared__ int curs[GROUP];
    __shared__ int sorted[ST2CAP];
    const int tid = threadIdx.x;
    const int n = cur2[gg];
    int* s = st2 + (size_t)gg * ST2CAP;
    cnt[tid] = 0;
    __syncthreads();
    for (int i = tid; i < n; i += 256) atomicAdd(&cnt[s[i] >> SHIFT], 1);
    __syncthreads();
    const int x = cnt[tid];
    for (int d = 1; d < 256; d <<= 1) {
        const int v = (tid >= d) ? cnt[tid - d] : 0;
        __syncthreads();
        cnt[tid] += v;
        __syncthreads();
    }
    const int excl = cnt[tid] - x;
    if (tid < GROUP) { loc[tid] = excl; curs[tid] = excl; }
    __syncthreads();
    for (int i = tid; i < n; i += 256) {
        const int e = s[i];
        const int pos = atomicAdd(&curs[e >> SHIFT], 1);
        sorted[pos] = e;
    }
    __syncthreads();
    for (int i = tid; i < n; i += 256) s[i] = sorted[i];
    if (tid < GROUP) {
        row_beg[gg * GROUP + tid] = gg * ST2CAP + loc[tid];
        row_cnt[gg * GROUP + tid] = x;
    }
}

// Fused: blocks [0,800) entity; [800,1200) mat-col; [1200,1600) mat-row.
__global__ __launch_bounds__(256) void sort_all(
        int* __restrict__ st2_e, const int* __restrict__ cur2_e,
        int* __restrict__ beg_e, int* __restrict__ cnt_e,
        int* __restrict__ stC2, const int* __restrict__ cur2_c,
        int* __restrict__ beg_c, int* __restrict__ cnt_c,
        int* __restrict__ stR2, const int* __restrict__ cur2_r,
        int* __restrict__ beg_r, int* __restrict__ cnt_r) {
    const int b = blockIdx.x;
    if (b < 800)       group_sort_body<22>(st2_e, cur2_e, b, beg_e, cnt_e);
    else if (b < 1200) group_sort_body<16>(stC2, cur2_c, b - 800, beg_c, cnt_c);
    else               group_sort_body<16>(stR2, cur2_r, b - 1200, beg_r, cnt_r);
}

// ---------------------------------------------------------------------------
// Fused pull (r17, proven). MASKS REQUIRED (r9-11 faults = dropped mask).
// ---------------------------------------------------------------------------
__global__ void pull_ei_kernel(
        const float* __restrict__ ent, const float* __restrict__ wgt,
        const int* __restrict__ beg_e, const int* __restrict__ cnt_e,
        const int* __restrict__ ids_e, float* __restrict__ out_e,
        const float* __restrict__ uemb,
        const int* __restrict__ beg_c, const int* __restrict__ cnt_c,
        const int* __restrict__ ids_c, float* __restrict__ iu_out) {
    const int lane = threadIdx.x & 63;
    if (blockIdx.x < 25000) {
        const int wid = (blockIdx.x * 256 + threadIdx.x) >> 6;
        const int beg = beg_e[wid], nc = cnt_e[wid];
        const int end = beg + nc;
        float acc = 0.f;
        for (int base = beg; base < end; base += 64) {
            const int k = base + lane;
            int v = 0;
            if (k < end) v = __builtin_nontemporal_load(ids_e + k);
            const int nn = min(64, end - base);
            int kk = 0;
            for (; kk + 4 <= nn; kk += 4) {
                const int v0 = __shfl(v, kk),     v1 = __shfl(v, kk + 1);
                const int v2 = __shfl(v, kk + 2), v3 = __shfl(v, kk + 3);
                const float a0 = ent[(size_t)(v0 & 0x1FFFF) * DD + lane] * wgt[((v0 >> 17) & 31) * DD + lane];
                const float a1 = ent[(size_t)(v1 & 0x1FFFF) * DD + lane] * wgt[((v1 >> 17) & 31) * DD + lane];
                const float a2 = ent[(size_t)(v2 & 0x1FFFF) * DD + lane] * wgt[((v2 >> 17) & 31) * DD + lane];
                const float a3 = ent[(size_t)(v3 & 0x1FFFF) * DD + lane] * wgt[((v3 >> 17) & 31) * DD + lane];
                acc += a0 + a1 + a2 + a3;
            }
            for (; kk < nn; ++kk) {
                const int vv = __shfl(v, kk);
                acc += ent[(size_t)(vv & 0x1FFFF) * DD + lane] * wgt[((vv >> 17) & 31) * DD + lane];
            }
        }
        out_e[(size_t)wid * DD + lane] = acc / fmaxf((float)nc, 1.0f);
    } else {
        const int wid = ((blockIdx.x - 25000) * 256 + threadIdx.x) >> 6;
        if (wid >= N_ITEMS) return;
        const float w0 = wgt[lane];
        const int beg = beg_c[wid], nc = cnt_c[wid];
        const int end = beg + nc;
        float acc = 0.f;
        for (int base = beg; base < end; base += 64) {
            const int k = base + lane;
            int v = 0;
            if (k < end) v = __builtin_nontemporal_load(ids_c + k);
            const int nn = min(64, end - base);
            int kk = 0;
            for (; kk + 4 <= nn; kk += 4) {
                const int v0 = __shfl(v, kk),     v1 = __shfl(v, kk + 1);
                const int v2 = __shfl(v, kk + 2), v3 = __shfl(v, kk + 3);
                acc += uemb[(size_t)(v0 & 0xFFFF) * DD + lane] + uemb[(size_t)(v1 & 0xFFFF) * DD + lane]
                     + uemb[(size_t)(v2 & 0xFFFF) * DD + lane] + uemb[(size_t)(v3 & 0xFFFF) * DD + lane];
            }
            for (; kk < nn; ++kk) {
                const int vv = __shfl(v, kk);
                acc += uemb[(size_t)(vv & 0xFFFF) * DD + lane];
            }
        }
        iu_out[(size_t)wid * DD + lane] = acc * w0 / fmaxf((float)nc, 1.0f);
    }
}

__global__ void pull_user_kernel(const float* __restrict__ fus,
                                 const int* __restrict__ row_beg,
                                 const int* __restrict__ row_cnt,
                                 const int* __restrict__ ids,
                                 float* __restrict__ uout) {
    const int lane = threadIdx.x & 63;
    const int wid = (blockIdx.x * blockDim.x + threadIdx.x) >> 6;
    if (wid >= N_USERS) return;
    const int beg = row_beg[wid], nc = row_cnt[wid];
    const int end = beg + nc;
    float acc = 0.f;
    for (int base = beg; base < end; base += 64) {
        const int k = base + lane;
        int v = 0;
        if (k < end) v = __builtin_nontemporal_load(ids + k);
        const int nn = min(64, end - base);
        int kk = 0;
        for (; kk + 4 <= nn; kk += 4) {
            const int v0 = __shfl(v, kk),     v1 = __shfl(v, kk + 1);
            const int v2 = __shfl(v, kk + 2), v3 = __shfl(v, kk + 3);
            acc += fus[(size_t)(v0 & 0xFFFF) * DD + lane] + fus[(size_t)(v1 & 0xFFFF) * DD + lane]
                 + fus[(size_t)(v2 & 0xFFFF) * DD + lane] + fus[(size_t)(v3 & 0xFFFF) * DD + lane];
        }
        for (; kk < nn; ++kk) {
            const int vv = __shfl(v, kk);
            acc += fus[(size_t)(vv & 0xFFFF) * DD + lane];
        }
    }
    uout[(size_t)wid * DD + lane] = acc;
}

// ---------------------------------------------------------------------------
// Gate + fusion, in place on d_out. 32 items per block (G1/G2 staged once).
// ---------------------------------------------------------------------------
__global__ __launch_bounds__(256) void gate_fusion_kernel(
        float* __restrict__ kg_fus, const float* __restrict__ iu,
        const float* __restrict__ g1, const float* __restrict__ g2) {
    __shared__ float G1[64 * 65];
    __shared__ float G2[64 * 65];
    __shared__ float xs1[4][64];
    __shared__ float xs2[4][64];

    const int tid = threadIdx.x;
    for (int i = tid; i < 64 * 64; i += 256) {
        const int r = i >> 6, c = i & 63;
        G1[r * 65 + c] = g1[i];
        G2[r * 65 + c] = g2[i];
    }
    const int il = tid >> 6;
    const int j = tid & 63;
    const int base = blockIdx.x * 32;
    __syncthreads();

    for (int it = 0; it < 8; ++it) {
        const int item = base + it * 4 + il;
        const bool ok = item < N_ITEMS;
        float x1 = 0.f, x2 = 0.f;
        if (ok) {
            x1 = kg_fus[(size_t)item * DD + j];
            x2 = iu[(size_t)item * DD + j];
        }
        xs1[il][j] = x1;
        xs2[il][j] = x2;
        __syncthreads();
        float s = 0.0f;
        #pragma unroll
        for (int k = 0; k < 64; ++k) {
            s += xs1[il][k] * G1[j * 65 + k];
            s += xs2[il][k] * G2[j * 65 + k];
        }
        const float gi = 1.0f / (1.0f + __expf(-s));
        if (ok) kg_fus[(size_t)item * DD + j] = gi * x1 + (1.0f - gi) * x2;
        __syncthreads();
    }
}

extern "C" void kernel_launch(void* const* d_in, const int* in_sizes, int n_in,
                              void* d_out, int out_size, void* d_ws, size_t ws_size,
                              hipStream_t stream) {
    const float* entity_emb = (const float*)d_in[0];
    const float* user_emb   = (const float*)d_in[1];
    const int*   edge_index = (const int*)d_in[2];
    const int*   edge_type  = (const int*)d_in[3];
    const int*   mat_row    = (const int*)d_in[4];
    const int*   mat_col    = (const int*)d_in[5];
    const float* weight     = (const float*)d_in[7];
    const float* gate1_w    = (const float*)d_in[8];
    const float* gate2_w    = (const float*)d_in[9];

    float* out = (float*)d_out;
    float* out_fusion = out;                       // rows [0, 50000)
    float* out_entity = out;                       // rows [0, 100000)
    float* out_user   = out + (size_t)N_ENT * DD;  // temp i_u_agg, then user_agg

    // workspace (ints), peak 36.0 MB (<= 39 MB proven). Aliasing:
    //   stC/stR are FRESH (written concurrently with st_ek/st_ev in fused L1).
    //   stC2 aliases st_ek, stR2 aliases st_ev (both dead after bucket_edge_L2,
    //   written by bucket_mat_L2 strictly after).
    int* W      = (int*)d_ws;
    int* cur_e  = W + 0;         // 8
    int* cur_c  = W + 8;         // 8
    int* cur_r  = W + 16;        // 8
    int* cur2_e = W + 24;        // 800
    int* cur2_c = W + 824;       // 400
    int* cur2_r = W + 1224;      // 400   (cursors end 1624, pad to 2048)
    int* st_ek  = W + 2048;                    // 2,097,152
    int* st_ev  = st_ek + 2097152;             // 2,097,152
    int* stC    = st_ev + 2097152;             // 1,048,576 (fresh)
    int* stR    = stC + 1048576;               // 1,048,576 (fresh)
    int* st2_e  = stR + 1048576;               // 800*2880 = 2,304,000 (fresh)
    int* stC2   = st_ek;                       // 1,152,000 (aliases st_ek)
    int* stR2   = st_ev;                       // 1,152,000 (aliases st_ev)
    int* tabs   = st2_e + 2304000;             // 400,000
    int* beg_e  = tabs;            // 100,000
    int* cnt_e  = tabs + 100000;   // 100,000
    int* beg_c  = tabs + 200000;   // 50,000
    int* cnt_c  = tabs + 250000;   // 50,000
    int* beg_r  = tabs + 300000;   // 50,000
    int* cnt_r  = tabs + 350000;   // 50,000  (end = 8,998,376 ints = 36.0 MB)

    const int* head = edge_index;
    const int* tail = edge_index + NE;

    // 1. zero all cursors (8 KB)
    (void)hipMemsetAsync(W, 0, 2048 * sizeof(int), stream);

    // 2. fused L1 bucketing: edge + mat in one launch
    bucket_L1_fused<<<768, 256, 0, stream>>>(head, tail, edge_type,
                                             st_ek, st_ev, cur_e,
                                             mat_row, mat_col,
                                             stC, cur_c, stR, cur_r);
    // 3. edge L2 (consumes st_ek/st_ev — after this they're dead)
    bucket_edge_L2<<<256, 1024, 0, stream>>>(st_ek, st_ev, cur_e, st2_e, cur2_e);
    // 4-5. mat L2 (writes stC2/stR2 over the dead st_ek/st_ev regions)
    bucket_mat_L2<<<256, 1024, 0, stream>>>(stC, cur_c, stC2, cur2_c);
    bucket_mat_L2<<<256, 1024, 0, stream>>>(stR, cur_r, stR2, cur2_r);
    // 6. all group sorts
    sort_all<<<1600, 256, 0, stream>>>(st2_e, cur2_e, beg_e, cnt_e,
                                       stC2, cur2_c, beg_c, cnt_c,
                                       stR2, cur2_r, beg_r, cnt_r);
    // 7. fused entity + i_u pulls
    pull_ei_kernel<<<37500, 256, 0, stream>>>(entity_emb, weight,
                                              beg_e, cnt_e, st2_e, out_entity,
                                              user_emb, beg_c, cnt_c, stC2, out_user);
    // 8. gate + fusion
    gate_fusion_kernel<<<(N_ITEMS + 31) / 32, 256, 0, stream>>>(out_fusion, out_user,
                                                                gate1_w, gate2_w);
    // 9. user_agg
    pull_user_kernel<<<N_USERS / 4, 256, 0, stream>>>(out_fusion,
                                                      beg_r, cnt_r, stR2, out_user);
}

// Round 19
// 308.010 us; speedup vs baseline: 1.2243x; 1.1453x over previous
//
#include <hip/hip_runtime.h>
#include <hip/hip_bf16.h>

#define N_USERS   50000
#define N_ITEMS   50000
#define N_ENT     100000
#define NE        2000000
#define NNI       1000000
#define DD        64

#define PART_E    12500    // entity rows per XCD partition
#define PART_I    6250     // item/user rows per XCD partition
#define GROUP     125      // rows per sort group
#define NG_E      100      // groups per entity partition
#define NG_M      50       // groups per item/user partition

#define ECAP_E    262144   // per-XCD-bucket capacity, edges (mean 250000)
#define ECAP_M    131072   // per-XCD-bucket capacity, mat   (mean 125000)
#define ST2CAP    2880     // per-group capacity (mean 2500)
#define CHUNK     4096
#define CAPB      640      // L1 LDS per-bucket staging
#define GCAP      96       // L2 LDS per-group staging

// ---------------------------------------------------------------------------
// Fused L1 bucketing: blocks [0,512) = edge chain, [512,768) = mat chain.
// (proven r18)
// ---------------------------------------------------------------------------
__global__ __launch_bounds__(256) void bucket_L1_fused(
        const int* __restrict__ head, const int* __restrict__ tail,
        const int* __restrict__ etype,
        int* __restrict__ stK, int* __restrict__ stV, int* __restrict__ cur,
        const int* __restrict__ mrow, const int* __restrict__ mcol,
        int* __restrict__ stC, int* __restrict__ curC,
        int* __restrict__ stR, int* __restrict__ curR) {
    __shared__ int bufA[8][CAPB];
    __shared__ int bufB[8][CAPB];
    __shared__ int l1[8], l2[8], g1s[8], g2s[8];
    const int tid = threadIdx.x;
    const int lane = tid & 63;

    if (blockIdx.x < 512) {
        for (int cs = blockIdx.x * CHUNK; cs < NE; cs += 512 * CHUNK) {
            if (tid < 8) l1[tid] = 0;
            __syncthreads();
            const int ce = min(cs + CHUNK, NE);
            for (int i0 = cs; i0 < ce; i0 += 256) {
                const int i = i0 + tid;
                const bool valid = i < ce;
                int h = 0, v = 0, b = 8;
                if (valid) {
                    h = __builtin_nontemporal_load(head + i);
                    v = __builtin_nontemporal_load(tail + i) |
                        (__builtin_nontemporal_load(etype + i) << 17);
                    b = h / PART_E;
                }
                unsigned long long m[8];
                #pragma unroll
                for (int k = 0; k < 8; ++k) m[k] = __ballot(b == k);
                int base8 = 0;
                if (lane < 8) base8 = atomicAdd(&l1[lane], (int)__popcll(m[lane]));
                if (valid) {
                    const int mybase = __shfl(base8, b);
                    const int pos = mybase + (int)__popcll(m[b] & ((1ull << lane) - 1ull));
                    if (pos < CAPB) { bufA[b][pos] = h; bufB[b][pos] = v; }
                    else {
                        const int gp = atomicAdd(&cur[b], 1);
                        stK[(size_t)b * ECAP_E + gp] = h;
                        stV[(size_t)b * ECAP_E + gp] = v;
                    }
                }
            }
            __syncthreads();
            if (tid < 8) g1s[tid] = atomicAdd(&cur[tid], min(l1[tid], CAPB));
            __syncthreads();
            for (int b = 0; b < 8; ++b) {
                const int nf = min(l1[b], CAPB);
                int* dK = stK + (size_t)b * ECAP_E + g1s[b];
                int* dV = stV + (size_t)b * ECAP_E + g1s[b];
                for (int j = tid; j < nf; j += 256) { dK[j] = bufA[b][j]; dV[j] = bufB[b][j]; }
            }
            __syncthreads();
        }
    } else {
        const int mb = blockIdx.x - 512;
        for (int cs = mb * CHUNK; cs < NNI; cs += 256 * CHUNK) {
            if (tid < 8) { l1[tid] = 0; l2[tid] = 0; }
            __syncthreads();
            const int ce = min(cs + CHUNK, NNI);
            for (int i0 = cs; i0 < ce; i0 += 256) {
                const int i = i0 + tid;
                const bool valid = i < ce;
                int r = 0, c = 0, bc = 8, br = 8;
                if (valid) {
                    r = __builtin_nontemporal_load(mrow + i);
                    c = __builtin_nontemporal_load(mcol + i);
                    bc = c / PART_I;
                    br = r / PART_I;
                }
                unsigned long long mc[8], mrr[8];
                #pragma unroll
                for (int k = 0; k < 8; ++k) { mc[k] = __ballot(bc == k); mrr[k] = __ballot(br == k); }
                int bc8 = 0, br8 = 0;
                if (lane < 8) {
                    bc8 = atomicAdd(&l1[lane], (int)__popcll(mc[lane]));
                    br8 = atomicAdd(&l2[lane], (int)__popcll(mrr[lane]));
                }
                if (valid) {
                    const unsigned long long lt = (1ull << lane) - 1ull;
                    int pos = __shfl(bc8, bc) + (int)__popcll(mc[bc] & lt);
                    const int vc = (int)(((unsigned)c << 16) | (unsigned)r);
                    if (pos < CAPB) bufA[bc][pos] = vc;
                    else stC[(size_t)bc * ECAP_M + atomicAdd(&curC[bc], 1)] = vc;
                    pos = __shfl(br8, br) + (int)__popcll(mrr[br] & lt);
                    const int vr = (int)(((unsigned)r << 16) | (unsigned)c);
                    if (pos < CAPB) bufB[br][pos] = vr;
                    else stR[(size_t)br * ECAP_M + atomicAdd(&curR[br], 1)] = vr;
                }
            }
            __syncthreads();
            if (tid < 8)       g1s[tid]     = atomicAdd(&curC[tid],     min(l1[tid],     CAPB));
            else if (tid < 16) g2s[tid - 8] = atomicAdd(&curR[tid - 8], min(l2[tid - 8], CAPB));
            __syncthreads();
            for (int b = 0; b < 8; ++b) {
                int nf = min(l1[b], CAPB);
                int* d = stC + (size_t)b * ECAP_M + g1s[b];
                for (int j = tid; j < nf; j += 256) d[j] = bufA[b][j];
                nf = min(l2[b], CAPB);
                d = stR + (size_t)b * ECAP_M + g2s[b];
                for (int j = tid; j < nf; j += 256) d[j] = bufB[b][j];
            }
            __syncthreads();
        }
    }
}

// ---------------------------------------------------------------------------
// Shared L2 bodies (byte-identical logic to r18's proven kernels).
// ---------------------------------------------------------------------------
__device__ __forceinline__ void edge_L2_body(
        const int* __restrict__ sK, const int* __restrict__ sV, int n,
        int bi, int nb, int pbase, int part, int* __restrict__ st2,
        int* __restrict__ cur2p,
        int (*buf)[GCAP], int* lcnt, int nthreads) {
    const int tid = threadIdx.x, w = tid >> 6, lane = tid & 63;
    const int nw = nthreads >> 6;
    for (int cs = bi * CHUNK; cs < n; cs += nb * CHUNK) {
        for (int t = tid; t < NG_E; t += nthreads) lcnt[t] = 0;
        __syncthreads();
        const int ce = min(cs + CHUNK, n);
        for (int i = cs + tid; i < ce; i += nthreads) {
            const int local = __builtin_nontemporal_load(sK + i) - pbase;
            const int g = local / GROUP;
            const int rig = local - g * GROUP;
            const int entry = __builtin_nontemporal_load(sV + i) | (rig << 22);
            const int pos = atomicAdd(&lcnt[g], 1);
            if (pos < GCAP) buf[g][pos] = entry;
            else st2[(size_t)(part * NG_E + g) * ST2CAP + atomicAdd(&cur2p[g], 1)] = entry;
        }
        __syncthreads();
        for (int gi = w; gi < NG_E; gi += nw) {
            const int nf = min(lcnt[gi], GCAP);
            int base = 0;
            if (lane == 0 && nf > 0) base = atomicAdd(&cur2p[gi], nf);
            base = __shfl(base, 0);
            int* d = st2 + (size_t)(part * NG_E + gi) * ST2CAP + base;
            for (int j = lane; j < nf; j += 64) d[j] = buf[gi][j];
        }
        __syncthreads();
    }
}

__device__ __forceinline__ void mat_L2_body(
        const int* __restrict__ s, int n,
        int bi, int nb, int pbase, int part, int* __restrict__ st2,
        int* __restrict__ cur2p,
        int (*buf)[GCAP], int* lcnt, int nthreads) {
    const int tid = threadIdx.x, w = tid >> 6, lane = tid & 63;
    const int nw = nthreads >> 6;
    for (int cs = bi * CHUNK; cs < n; cs += nb * CHUNK) {
        for (int t = tid; t < NG_M; t += nthreads) lcnt[t] = 0;
        __syncthreads();
        const int ce = min(cs + CHUNK, n);
        for (int i = cs + tid; i < ce; i += nthreads) {
            const unsigned u = (unsigned)__builtin_nontemporal_load(s + i);
            const int local = (int)(u >> 16) - pbase;
            const int g = local / GROUP;
            const int rig = local - g * GROUP;
            const int entry = (int)(u & 0xFFFFu) | (rig << 16);
            const int pos = atomicAdd(&lcnt[g], 1);
            if (pos < GCAP) buf[g][pos] = entry;
            else st2[(size_t)(part * NG_M + g) * ST2CAP + atomicAdd(&cur2p[g], 1)] = entry;
        }
        __syncthreads();
        for (int gi = w; gi < NG_M; gi += nw) {
            const int nf = min(lcnt[gi], GCAP);
            int base = 0;
            if (lane == 0 && nf > 0) base = atomicAdd(&cur2p[gi], nf);
            base = __shfl(base, 0);
            int* d = st2 + (size_t)(part * NG_M + gi) * ST2CAP + base;
            for (int j = lane; j < nf; j += 64) d[j] = buf[gi][j];
        }
        __syncthreads();
    }
}

// Serial variants (fallback path, identical dispatch shape to r18).
__global__ __launch_bounds__(1024) void bucket_edge_L2(
        const int* __restrict__ stK, const int* __restrict__ stV,
        const int* __restrict__ cur, int* __restrict__ st2,
        int* __restrict__ cur2) {
    __shared__ int buf[NG_E][GCAP];
    __shared__ int lcnt[NG_E];
    const int p = blockIdx.x & 7;
    edge_L2_body(stK + (size_t)p * ECAP_E, stV + (size_t)p * ECAP_E, cur[p],
                 blockIdx.x >> 3, gridDim.x >> 3, p * PART_E, p, st2,
                 cur2 + p * NG_E, buf, lcnt, 1024);
}

__global__ __launch_bounds__(1024) void bucket_mat_L2(
        const int* __restrict__ st, const int* __restrict__ cur8,
        int* __restrict__ st2, int* __restrict__ cur2) {
    __shared__ int buf[NG_M][GCAP];
    __shared__ int lcnt[NG_M];
    const int p = blockIdx.x & 7;
    mat_L2_body(st + (size_t)p * ECAP_M, cur8[p],
                blockIdx.x >> 3, gridDim.x >> 3, p * PART_I, p, st2,
                cur2 + p * NG_M, buf, lcnt, 1024);
}

// Fused variant: blocks [0,256) edge; [256,512) mat-col; [512,768) mat-row.
// Requires stC2/stR2 NOT to alias stK/stV (concurrent now).
__global__ __launch_bounds__(1024) void bucket_L2_fused(
        const int* __restrict__ stK, const int* __restrict__ stV,
        const int* __restrict__ cur, int* __restrict__ st2, int* __restrict__ cur2,
        const int* __restrict__ stC, const int* __restrict__ curC,
        int* __restrict__ stC2, int* __restrict__ cur2c,
        const int* __restrict__ stR, const int* __restrict__ curR,
        int* __restrict__ stR2, int* __restrict__ cur2r) {
    __shared__ int buf[NG_E][GCAP];
    __shared__ int lcnt[NG_E];
    if (blockIdx.x < 256) {
        const int p = blockIdx.x & 7;
        edge_L2_body(stK + (size_t)p * ECAP_E, stV + (size_t)p * ECAP_E, cur[p],
                     blockIdx.x >> 3, 32, p * PART_E, p, st2,
                     cur2 + p * NG_E, buf, lcnt, 1024);
    } else {
        const int dir = (blockIdx.x >= 512) ? 1 : 0;
        const int b = blockIdx.x - (dir ? 512 : 256);
        const int p = b & 7;
        mat_L2_body((dir ? stR : stC) + (size_t)p * ECAP_M, (dir ? curR : curC)[p],
                    b >> 3, 32, p * PART_I, p, dir ? stR2 : stC2,
                    (dir ? cur2r : cur2c) + p * NG_M, buf, lcnt, 1024);
    }
}

// ---------------------------------------------------------------------------
// Group-local LDS counting sort (proven). Entries retain rig bits.
// ---------------------------------------------------------------------------
template <int SHIFT>
__device__ __forceinline__ void group_sort_body(
        int* __restrict__ st2, const int* __restrict__ cur2, int gg,
        int* __restrict__ row_beg, int* __restrict__ row_cnt) {
    __shared__ int cnt[256];
    __shared__ int loc[GROUP];
    __shared__ int curs[GROUP];
    __shared__ int sorted[ST2CAP];
    const int tid = threadIdx.x;
    const int n = cur2[gg];
    int* s = st2 + (size_t)gg * ST2CAP;
    cnt[tid] = 0;
    __syncthreads();
    for (int i = tid; i < n; i += 256) atomicAdd(&cnt[s[i] >> SHIFT], 1);
    __syncthreads();
    const int x = cnt[tid];
    for (int d = 1; d < 256; d <<= 1) {
        const int v = (tid >= d) ? cnt[tid - d] : 0;
        __syncthreads();
        cnt[tid] += v;
        __syncthreads();
    }
    const int excl = cnt[tid] - x;
    if (tid < GROUP) { loc[tid] = excl; curs[tid] = excl; }
    __syncthreads();
    for (int i = tid; i < n; i += 256) {
        const int e = s[i];
        const int pos = atomicAdd(&curs[e >> SHIFT], 1);
        sorted[pos] = e;
    }
    __syncthreads();
    for (int i = tid; i < n; i += 256) s[i] = sorted[i];
    if (tid < GROUP) {
        row_beg[gg * GROUP + tid] = gg * ST2CAP + loc[tid];
        row_cnt[gg * GROUP + tid] = x;
    }
}

// Fused: blocks [0,800) entity; [800,1200) mat-col; [1200,1600) mat-row.
__global__ __launch_bounds__(256) void sort_all(
        int* __restrict__ st2_e, const int* __restrict__ cur2_e,
        int* __restrict__ beg_e, int* __restrict__ cnt_e,
        int* __restrict__ stC2, const int* __restrict__ cur2_c,
        int* __restrict__ beg_c, int* __restrict__ cnt_c,
        int* __restrict__ stR2, const int* __restrict__ cur2_r,
        int* __restrict__ beg_r, int* __restrict__ cnt_r) {
    const int b = blockIdx.x;
    if (b < 800)       group_sort_body<22>(st2_e, cur2_e, b, beg_e, cnt_e);
    else if (b < 1200) group_sort_body<16>(stC2, cur2_c, b - 800, beg_c, cnt_c);
    else               group_sort_body<16>(stR2, cur2_r, b - 1200, beg_r, cnt_r);
}

// ---------------------------------------------------------------------------
// Fused pull (r17/r18, proven). MASKS REQUIRED (r9-11 faults = dropped mask).
// ---------------------------------------------------------------------------
__global__ void pull_ei_kernel(
        const float* __restrict__ ent, const float* __restrict__ wgt,
        const int* __restrict__ beg_e, const int* __restrict__ cnt_e,
        const int* __restrict__ ids_e, float* __restrict__ out_e,
        const float* __restrict__ uemb,
        const int* __restrict__ beg_c, const int* __restrict__ cnt_c,
        const int* __restrict__ ids_c, float* __restrict__ iu_out) {
    const int lane = threadIdx.x & 63;
    if (blockIdx.x < 25000) {
        const int wid = (blockIdx.x * 256 + threadIdx.x) >> 6;
        const int beg = beg_e[wid], nc = cnt_e[wid];
        const int end = beg + nc;
        float acc = 0.f;
        for (int base = beg; base < end; base += 64) {
            const int k = base + lane;
            int v = 0;
            if (k < end) v = __builtin_nontemporal_load(ids_e + k);
            const int nn = min(64, end - base);
            int kk = 0;
            for (; kk + 4 <= nn; kk += 4) {
                const int v0 = __shfl(v, kk),     v1 = __shfl(v, kk + 1);
                const int v2 = __shfl(v, kk + 2), v3 = __shfl(v, kk + 3);
                const float a0 = ent[(size_t)(v0 & 0x1FFFF) * DD + lane] * wgt[((v0 >> 17) & 31) * DD + lane];
                const float a1 = ent[(size_t)(v1 & 0x1FFFF) * DD + lane] * wgt[((v1 >> 17) & 31) * DD + lane];
                const float a2 = ent[(size_t)(v2 & 0x1FFFF) * DD + lane] * wgt[((v2 >> 17) & 31) * DD + lane];
                const float a3 = ent[(size_t)(v3 & 0x1FFFF) * DD + lane] * wgt[((v3 >> 17) & 31) * DD + lane];
                acc += a0 + a1 + a2 + a3;
            }
            for (; kk < nn; ++kk) {
                const int vv = __shfl(v, kk);
                acc += ent[(size_t)(vv & 0x1FFFF) * DD + lane] * wgt[((vv >> 17) & 31) * DD + lane];
            }
        }
        out_e[(size_t)wid * DD + lane] = acc / fmaxf((float)nc, 1.0f);
    } else {
        const int wid = ((blockIdx.x - 25000) * 256 + threadIdx.x) >> 6;
        if (wid >= N_ITEMS) return;
        const float w0 = wgt[lane];
        const int beg = beg_c[wid], nc = cnt_c[wid];
        const int end = beg + nc;
        float acc = 0.f;
        for (int base = beg; base < end; base += 64) {
            const int k = base + lane;
            int v = 0;
            if (k < end) v = __builtin_nontemporal_load(ids_c + k);
            const int nn = min(64, end - base);
            int kk = 0;
            for (; kk + 4 <= nn; kk += 4) {
                const int v0 = __shfl(v, kk),     v1 = __shfl(v, kk + 1);
                const int v2 = __shfl(v, kk + 2), v3 = __shfl(v, kk + 3);
                acc += uemb[(size_t)(v0 & 0xFFFF) * DD + lane] + uemb[(size_t)(v1 & 0xFFFF) * DD + lane]
                     + uemb[(size_t)(v2 & 0xFFFF) * DD + lane] + uemb[(size_t)(v3 & 0xFFFF) * DD + lane];
            }
            for (; kk < nn; ++kk) {
                const int vv = __shfl(v, kk);
                acc += uemb[(size_t)(vv & 0xFFFF) * DD + lane];
            }
        }
        iu_out[(size_t)wid * DD + lane] = acc * w0 / fmaxf((float)nc, 1.0f);
    }
}

__global__ void pull_user_kernel(const float* __restrict__ fus,
                                 const int* __restrict__ row_beg,
                                 const int* __restrict__ row_cnt,
                                 const int* __restrict__ ids,
                                 float* __restrict__ uout) {
    const int lane = threadIdx.x & 63;
    const int wid = (blockIdx.x * blockDim.x + threadIdx.x) >> 6;
    if (wid >= N_USERS) return;
    const int beg = row_beg[wid], nc = row_cnt[wid];
    const int end = beg + nc;
    float acc = 0.f;
    for (int base = beg; base < end; base += 64) {
        const int k = base + lane;
        int v = 0;
        if (k < end) v = __builtin_nontemporal_load(ids + k);
        const int nn = min(64, end - base);
        int kk = 0;
        for (; kk + 4 <= nn; kk += 4) {
            const int v0 = __shfl(v, kk),     v1 = __shfl(v, kk + 1);
            const int v2 = __shfl(v, kk + 2), v3 = __shfl(v, kk + 3);
            acc += fus[(size_t)(v0 & 0xFFFF) * DD + lane] + fus[(size_t)(v1 & 0xFFFF) * DD + lane]
                 + fus[(size_t)(v2 & 0xFFFF) * DD + lane] + fus[(size_t)(v3 & 0xFFFF) * DD + lane];
        }
        for (; kk < nn; ++kk) {
            const int vv = __shfl(v, kk);
            acc += fus[(size_t)(vv & 0xFFFF) * DD + lane];
        }
    }
    uout[(size_t)wid * DD + lane] = acc;
}

// ---------------------------------------------------------------------------
// Gate + fusion, in place on d_out. 32 items per block (G1/G2 staged once).
// ---------------------------------------------------------------------------
__global__ __launch_bounds__(256) void gate_fusion_kernel(
        float* __restrict__ kg_fus, const float* __restrict__ iu,
        const float* __restrict__ g1, const float* __restrict__ g2) {
    __shared__ float G1[64 * 65];
    __shared__ float G2[64 * 65];
    __shared__ float xs1[4][64];
    __shared__ float xs2[4][64];

    const int tid = threadIdx.x;
    for (int i = tid; i < 64 * 64; i += 256) {
        const int r = i >> 6, c = i & 63;
        G1[r * 65 + c] = g1[i];
        G2[r * 65 + c] = g2[i];
    }
    const int il = tid >> 6;
    const int j = tid & 63;
    const int base = blockIdx.x * 32;
    __syncthreads();

    for (int it = 0; it < 8; ++it) {
        const int item = base + it * 4 + il;
        const bool ok = item < N_ITEMS;
        float x1 = 0.f, x2 = 0.f;
        if (ok) {
            x1 = kg_fus[(size_t)item * DD + j];
            x2 = iu[(size_t)item * DD + j];
        }
        xs1[il][j] = x1;
        xs2[il][j] = x2;
        __syncthreads();
        float s = 0.0f;
        #pragma unroll
        for (int k = 0; k < 64; ++k) {
            s += xs1[il][k] * G1[j * 65 + k];
            s += xs2[il][k] * G2[j * 65 + k];
        }
        const float gi = 1.0f / (1.0f + __expf(-s));
        if (ok) kg_fus[(size_t)item * DD + j] = gi * x1 + (1.0f - gi) * x2;
        __syncthreads();
    }
}

extern "C" void kernel_launch(void* const* d_in, const int* in_sizes, int n_in,
                              void* d_out, int out_size, void* d_ws, size_t ws_size,
                              hipStream_t stream) {
    const float* entity_emb = (const float*)d_in[0];
    const float* user_emb   = (const float*)d_in[1];
    const int*   edge_index = (const int*)d_in[2];
    const int*   edge_type  = (const int*)d_in[3];
    const int*   mat_row    = (const int*)d_in[4];
    const int*   mat_col    = (const int*)d_in[5];
    const float* weight     = (const float*)d_in[7];
    const float* gate1_w    = (const float*)d_in[8];
    const float* gate2_w    = (const float*)d_in[9];

    float* out = (float*)d_out;
    float* out_fusion = out;                       // rows [0, 50000)
    float* out_entity = out;                       // rows [0, 100000)
    float* out_user   = out + (size_t)N_ENT * DD;  // temp i_u_agg, then user_agg

    // workspace (ints). Base layout = r18 (36.0 MB, proven). Fused-L2 path
    // additionally needs fresh stC2/stR2 (no aliasing possible while edge-L2
    // runs concurrently): peak 45.3 MB, gated on ws_size.
    int* W      = (int*)d_ws;
    int* cur_e  = W + 0;         // 8
    int* cur_c  = W + 8;         // 8
    int* cur_r  = W + 16;        // 8
    int* cur2_e = W + 24;        // 800
    int* cur2_c = W + 824;       // 400
    int* cur2_r = W + 1224;      // 400   (cursors end 1624, pad to 2048)
    int* st_ek  = W + 2048;                    // 2,097,152
    int* st_ev  = st_ek + 2097152;             // 2,097,152
    int* stC    = st_ev + 2097152;             // 1,048,576 (fresh)
    int* stR    = stC + 1048576;               // 1,048,576 (fresh)
    int* st2_e  = stR + 1048576;               // 800*2880 = 2,304,000 (fresh)
    int* tabs   = st2_e + 2304000;             // 400,000
    int* beg_e  = tabs;            // 100,000
    int* cnt_e  = tabs + 100000;   // 100,000
    int* beg_c  = tabs + 200000;   // 50,000
    int* cnt_c  = tabs + 250000;   // 50,000
    int* beg_r  = tabs + 300000;   // 50,000
    int* cnt_r  = tabs + 350000;   // 50,000   (base end = 8,999,552)
    // fused-path fresh buffers:
    int* stC2f  = W + 9000000;                 // 400*2880 = 1,152,000
    int* stR2f  = stC2f + 1152000;             // 1,152,000 (end 11,304,000)
    // fallback aliases (legal only with serial L2 ordering):
    int* stC2a  = st_ek;
    int* stR2a  = st_ev;

    const bool fuseL2 = ws_size >= (size_t)11304000 * sizeof(int);
    int* stC2 = fuseL2 ? stC2f : stC2a;
    int* stR2 = fuseL2 ? stR2f : stR2a;

    const int* head = edge_index;
    const int* tail = edge_index + NE;

    // 1. zero all cursors (8 KB)
    (void)hipMemsetAsync(W, 0, 2048 * sizeof(int), stream);

    // 2. fused L1 bucketing: edge + mat in one launch
    bucket_L1_fused<<<768, 256, 0, stream>>>(head, tail, edge_type,
                                             st_ek, st_ev, cur_e,
                                             mat_row, mat_col,
                                             stC, cur_c, stR, cur_r);
    // 3. L2 bucketing
    if (fuseL2) {
        bucket_L2_fused<<<768, 1024, 0, stream>>>(st_ek, st_ev, cur_e, st2_e, cur2_e,
                                                  stC, cur_c, stC2, cur2_c,
                                                  stR, cur_r, stR2, cur2_r);
    } else {
        bucket_edge_L2<<<256, 1024, 0, stream>>>(st_ek, st_ev, cur_e, st2_e, cur2_e);
        bucket_mat_L2<<<256, 1024, 0, stream>>>(stC, cur_c, stC2, cur2_c);
        bucket_mat_L2<<<256, 1024, 0, stream>>>(stR, cur_r, stR2, cur2_r);
    }
    // 4. all group sorts
    sort_all<<<1600, 256, 0, stream>>>(st2_e, cur2_e, beg_e, cnt_e,
                                       stC2, cur2_c, beg_c, cnt_c,
                                       stR2, cur2_r, beg_r, cnt_r);
    // 5. fused entity + i_u pulls
    pull_ei_kernel<<<37500, 256, 0, stream>>>(entity_emb, weight,
                                              beg_e, cnt_e, st2_e, out_entity,
                                              user_emb, beg_c, cnt_c, stC2, out_user);
    // 6. gate + fusion
    gate_fusion_kernel<<<(N_ITEMS + 31) / 32, 256, 0, stream>>>(out_fusion, out_user,
                                                                gate1_w, gate2_w);
    // 7. user_agg
    pull_user_kernel<<<N_USERS / 4, 256, 0, stream>>>(out_fusion,
                                                      beg_r, cnt_r, stR2, out_user);
}